// Round 13
// baseline (1674.974 us; speedup 1.0000x reference)
//
#include <hip/hip_runtime.h>
#include <math.h>

// Problem constants
constexpr int B_  = 64;
constexpr int S_  = 512;
constexpr int H_  = 768;
constexpr int H2_ = 1536;   // 2H
constexpr int G3_ = 2304;   // 3H
constexpr int OP_ = 18;
constexpr int C_  = 24;
constexpr int M_  = 16;
constexpr int E_  = 8;
constexpr int A_  = 3;
constexpr int K_  = 48;     // C+M+E
constexpr int HH_ = 384;    // H/2

using f32x4  = __attribute__((ext_vector_type(4))) float;
using short8 = __attribute__((ext_vector_type(8))) short;

#define MFMA16(a, b, c) __builtin_amdgcn_mfma_f32_16x16x32_bf16((a), (b), (c), 0, 0, 0)

// Split f32 into bf16 hi (truncate) + bf16 lo (residual, truncate).
__device__ __forceinline__ void split1(float x, short& h, short& l)
{
    union { float f; unsigned u; } a; a.f = x;
    h = (short)(a.u >> 16);
    union { unsigned u; float f; } hb; hb.u = a.u & 0xffff0000u;
    union { float f; unsigned u; } r; r.f = x - hb.f;
    l = (short)(r.u >> 16);
}

__device__ __forceinline__ void cvt8(float4 p0, float4 p1, short8& hi, short8& lo)
{
    float x[8] = {p0.x, p0.y, p0.z, p0.w, p1.x, p1.y, p1.z, p1.w};
    #pragma unroll
    for (int e = 0; e < 8; ++e) { short h, l; split1(x[e], h, l); hi[e] = h; lo[e] = l; }
}

// Bulk f32 -> bf16 hi/lo splitter (weights, once per launch)
__global__ void k_split4(const float* __restrict__ src, short* __restrict__ hi,
                         short* __restrict__ lo, int n4)
{
    int t = blockIdx.x * 256 + threadIdx.x;
    if (t >= n4) return;
    float4 v = ((const float4*)src)[t];
    float x[4] = {v.x, v.y, v.z, v.w};
    short h[4], l[4];
    #pragma unroll
    for (int e = 0; e < 4; ++e) split1(x[e], h[e], l[e]);
    ((short4*)hi)[t] = make_short4(h[0], h[1], h[2], h[3]);
    ((short4*)lo)[t] = make_short4(l[0], l[1], l[2], l[3]);
}

// ---------------------------------------------------------------------------
// GRU dual GEMM via MFMA: grid(288) x 256 thr (4 waves), 16-col tiles.
// bx<144: gi cols = x @ Wih^T; else gh. Waves split K=768 4 ways,
// in-register accum, LDS reduce, wave0 stores f32 to gigh.
// vs R10 (32-col/144blk): 2x waves (1152) -> all 256 CUs busy, deeper
// per-wave load pipeline (60 loads, acc=16 VGPR). Per-output K order
// unchanged -> bit-identical to R10/R12.
// ---------------------------------------------------------------------------
__global__ __launch_bounds__(256) void k_gru_mfma(
    const short* __restrict__ xhi, const short* __restrict__ xlo, long ldx, int pickmode,
    const int* __restrict__ gopd, int i, int jm1,
    const short* __restrict__ pchi, const short* __restrict__ pclo,
    const short* __restrict__ pnhi, const short* __restrict__ pnlo,
    const short* __restrict__ pvhi, const short* __restrict__ pvlo,
    const short* __restrict__ hhi, const short* __restrict__ hlo, long ldh,
    const short* __restrict__ Wih_hi, const short* __restrict__ Wih_lo,
    const short* __restrict__ Whh_hi, const short* __restrict__ Whh_lo,
    float* __restrict__ C)
{
    const int tid  = threadIdx.x;
    const int lane = tid & 63;
    const int w    = tid >> 6;
    const int bx   = blockIdx.x;
    const bool hside = bx >= 144;
    const int n0 = (hside ? bx - 144 : bx) * 16;
    const int koff = (lane >> 4) * 8;

    const short* ahi[4]; const short* alo[4];
    #pragma unroll
    for (int rt = 0; rt < 4; ++rt) {
        int r = rt * 16 + (lane & 15);
        long off;
        const short *bh_, *bl_;
        if (hside) { bh_ = hhi; bl_ = hlo; off = (long)r * ldh; }
        else if (!pickmode) { bh_ = xhi; bl_ = xlo; off = (long)r * ldx; }
        else {
            int idx = gopd[(r * E_ + i) * A_ + jm1];
            if (idx < C_)           { bh_ = pchi; bl_ = pclo; off = (long)idx * H_; }
            else if (idx < C_ + M_) { bh_ = pnhi; bl_ = pnlo; off = ((long)r * M_ + (idx - C_)) * H_; }
            else                    { bh_ = pvhi; bl_ = pvlo; off = ((long)r * E_ + (idx - C_ - M_)) * H_; }
        }
        ahi[rt] = bh_ + off + koff;
        alo[rt] = bl_ + off + koff;
    }
    const short* WH = hside ? Whh_hi : Wih_hi;
    const short* WL = hside ? Whh_lo : Wih_lo;
    const long woff = (long)(n0 + (lane & 15)) * H_ + koff;
    const short* whi = WH + woff;
    const short* wlo = WL + woff;

    f32x4 acc[4];
    #pragma unroll
    for (int rt = 0; rt < 4; ++rt) acc[rt] = (f32x4){0.f, 0.f, 0.f, 0.f};

    for (int kt = w * 6; kt < w * 6 + 6; ++kt) {
        const int kb = kt * 32;
        short8 Ah[4], Al[4];
        #pragma unroll
        for (int rt = 0; rt < 4; ++rt) {
            Ah[rt] = *(const short8*)(ahi[rt] + kb);
            Al[rt] = *(const short8*)(alo[rt] + kb);
        }
        short8 Bh = *(const short8*)(whi + kb);
        short8 Bl = *(const short8*)(wlo + kb);
        #pragma unroll
        for (int rt = 0; rt < 4; ++rt) {
            acc[rt] = MFMA16(Ah[rt], Bh, acc[rt]);
            acc[rt] = MFMA16(Ah[rt], Bl, acc[rt]);
            acc[rt] = MFMA16(Al[rt], Bh, acc[rt]);
        }
    }

    __shared__ f32x4 Lr[12][64];
    if (w > 0) {
        #pragma unroll
        for (int rt = 0; rt < 4; ++rt)
            Lr[(w - 1) * 4 + rt][lane] = acc[rt];
    }
    __syncthreads();
    if (w == 0) {
        float* Cb = C + (hside ? 2304 : 0) + n0;
        #pragma unroll
        for (int rt = 0; rt < 4; ++rt) {
            f32x4 s = acc[rt];
            s = s + Lr[rt][lane] + Lr[4 + rt][lane] + Lr[8 + rt][lane];
            int col = lane & 15;
            int rb  = rt * 16 + ((lane >> 4) << 2);
            #pragma unroll
            for (int r = 0; r < 4; ++r)
                Cb[(long)(rb + r) * 4608 + col] = s[r];
        }
    }
}

// ---------------------------------------------------------------------------
// Projection GEMM: A f32 (cvt in-reg, runs once), W pre-split bf16.
// ---------------------------------------------------------------------------
__global__ __launch_bounds__(256) void k_proj_mfma(
    const float* __restrict__ Ab, long lda, const int* __restrict__ gidx, int Mm,
    const short* __restrict__ Whi, const short* __restrict__ Wlo, int wld,
    float* __restrict__ C, int ldc)
{
    const int tid  = threadIdx.x;
    const int lane = tid & 63;
    const int w    = tid >> 6;
    const int n0 = blockIdx.x * 64;
    const int r0 = blockIdx.y * 64;
    const int koff = (lane >> 4) * 8;

    const float* arow[4];
    #pragma unroll
    for (int rt = 0; rt < 4; ++rt) {
        int r = r0 + rt * 16 + (lane & 15);
        int rr = r < Mm ? r : (Mm - 1);
        const float* s = gidx ? (Ab + (long)gidx[rr] * lda) : (Ab + (long)rr * lda);
        arow[rt] = s + koff;
    }
    const short* whi[4]; const short* wlo[4];
    #pragma unroll
    for (int nt = 0; nt < 4; ++nt) {
        long off = (long)(n0 + nt * 16 + (lane & 15)) * wld + koff;
        whi[nt] = Whi + off; wlo[nt] = Wlo + off;
    }

    f32x4 acc[4][4];
    #pragma unroll
    for (int rt = 0; rt < 4; ++rt)
        #pragma unroll
        for (int nt = 0; nt < 4; ++nt) acc[rt][nt] = (f32x4){0.f, 0.f, 0.f, 0.f};

    for (int kt = w * 12; kt < w * 12 + 12; ++kt) {
        const int kb = kt * 32;
        short8 ah[4], al[4];
        #pragma unroll
        for (int rt = 0; rt < 4; ++rt) {
            float4 p0 = *(const float4*)(arow[rt] + kb);
            float4 p1 = *(const float4*)(arow[rt] + kb + 4);
            cvt8(p0, p1, ah[rt], al[rt]);
        }
        #pragma unroll
        for (int nt = 0; nt < 4; ++nt) {
            short8 Bh = *(const short8*)(whi[nt] + kb);
            short8 Bl = *(const short8*)(wlo[nt] + kb);
            #pragma unroll
            for (int rt = 0; rt < 4; ++rt) {
                acc[rt][nt] = MFMA16(ah[rt], Bh, acc[rt][nt]);
                acc[rt][nt] = MFMA16(ah[rt], Bl, acc[rt][nt]);
                acc[rt][nt] = MFMA16(al[rt], Bh, acc[rt][nt]);
            }
        }
    }

    __shared__ f32x4 Lr[48][64];
    if (w > 0) {
        #pragma unroll
        for (int rt = 0; rt < 4; ++rt)
            #pragma unroll
            for (int nt = 0; nt < 4; ++nt)
                Lr[(w - 1) * 16 + rt * 4 + nt][lane] = acc[rt][nt];
    }
    __syncthreads();
    if (w == 0) {
        #pragma unroll
        for (int rt = 0; rt < 4; ++rt)
            #pragma unroll
            for (int nt = 0; nt < 4; ++nt) {
                int f = rt * 4 + nt;
                f32x4 s = acc[rt][nt];
                s = s + Lr[f][lane] + Lr[16 + f][lane] + Lr[32 + f][lane];
                int col = n0 + nt * 16 + (lane & 15);
                int rb  = r0 + rt * 16 + ((lane >> 4) << 2);
                #pragma unroll
                for (int r = 0; r < 4; ++r)
                    if (rb + r < Mm) C[(long)(rb + r) * ldc + col] = s[r];
            }
    }
}

// Gates (layer-0): read gi|gh, biases, hnew = (1-z)*n + z*h (+ shadow)
__global__ void k_gates2(const float* __restrict__ GI,
                         const float* __restrict__ h, long ldh,
                         const float* __restrict__ bih, const float* __restrict__ bhh,
                         float* __restrict__ hnew,
                         short* __restrict__ hnhi, short* __restrict__ hnlo)
{
    int t = blockIdx.x * 256 + threadIdx.x;       // 64*768
    int b = t / 768, c = t - b * 768;
    const float* gb = GI + (long)b * 4608;
    float ir  = gb[c]        + bih[c];
    float iz  = gb[768 + c]  + bih[768 + c];
    float in_ = gb[1536 + c] + bih[1536 + c];
    float hr  = gb[2304 + c] + bhh[c];
    float hz  = gb[3072 + c] + bhh[768 + c];
    float hn  = gb[3840 + c] + bhh[1536 + c];
    float r  = 1.f / (1.f + expf(-(ir + hr)));
    float z_ = 1.f / (1.f + expf(-(iz + hz)));
    float n  = tanhf(in_ + r * hn);
    float hp = h[(long)b * ldh + c];
    float v = (1.f - z_) * n + z_ * hp;
    hnew[t] = v;
    short sh, sl; split1(v, sh, sl);
    hnhi[t] = sh; hnlo[t] = sl;
}

// Add bias then LayerNorm each 768-wide row of X in place (+ shadow).
__global__ void k_ln2(float* __restrict__ X, const float* __restrict__ bias,
                      const float* __restrict__ g, const float* __restrict__ be,
                      short* __restrict__ Xhi, short* __restrict__ Xlo)
{
    int row = blockIdx.x, tid = threadIdx.x;
    __shared__ float red[256];
    float* xr = X + (long)row * 768;
    float v[3];
    #pragma unroll
    for (int it = 0; it < 3; ++it) {
        int c2 = tid + it * 256;
        v[it] = xr[c2] + bias[c2];
    }
    float s = v[0] + v[1] + v[2];
    red[tid] = s; __syncthreads();
    for (int o = 128; o > 0; o >>= 1) { if (tid < o) red[tid] += red[tid + o]; __syncthreads(); }
    float mu = red[0] / 768.f;
    __syncthreads();
    float vv = 0.f;
    #pragma unroll
    for (int it = 0; it < 3; ++it) { float d = v[it] - mu; vv += d * d; }
    red[tid] = vv; __syncthreads();
    for (int o = 128; o > 0; o >>= 1) { if (tid < o) red[tid] += red[tid + o]; __syncthreads(); }
    float inv = 1.f / sqrtf(red[0] / 768.f + 1e-5f);
    #pragma unroll
    for (int it = 0; it < 3; ++it) {
        int c2 = tid + it * 256;
        float o2 = (v[it] - mu) * inv * g[c2] + be[c2];
        xr[c2] = o2;
        short sh, sl; split1(o2, sh, sl);
        Xhi[(long)row * 768 + c2] = sh;
        Xlo[(long)row * 768 + c2] = sl;
    }
}

// ---------------------------------------------------------------------------
// Fused op head with optional cg-gates-L1 prologue (do_gates).
// ---------------------------------------------------------------------------
__global__ __launch_bounds__(256) void k_ophead_fused(
    int do_gates,
    const float* __restrict__ GI,
    const float* __restrict__ bihg, const float* __restrict__ bhhg,
    const float* __restrict__ hp, long ldhp,
    float* __restrict__ cvf, short* __restrict__ cvhi, short* __restrict__ cvlo,
    const float* __restrict__ W1, const float* __restrict__ b1,
    const float* __restrict__ W2, const float* __restrict__ b2,
    float* __restrict__ op_out, int i)
{
    int b = blockIdx.x, tid = threadIdx.x;
    __shared__ float xs[768];
    __shared__ float hs[384];

    if (do_gates) {
        const float* gb = GI + (long)b * 4608;
        #pragma unroll
        for (int it = 0; it < 3; ++it) {
            int c2 = tid + it * 256;
            float ir  = gb[c2]        + bihg[c2];
            float iz  = gb[768 + c2]  + bihg[768 + c2];
            float in_ = gb[1536 + c2] + bihg[1536 + c2];
            float hr  = gb[2304 + c2] + bhhg[c2];
            float hz  = gb[3072 + c2] + bhhg[768 + c2];
            float hn  = gb[3840 + c2] + bhhg[1536 + c2];
            float r  = 1.f / (1.f + expf(-(ir + hr)));
            float z_ = 1.f / (1.f + expf(-(iz + hz)));
            float n  = tanhf(in_ + r * hn);
            float hpv = hp[(long)b * ldhp + c2];
            float v = (1.f - z_) * n + z_ * hpv;
            xs[c2] = v;
            cvf[(long)b * 768 + c2] = v;
            short sh, sl; split1(v, sh, sl);
            cvhi[(long)b * 768 + c2] = sh;
            cvlo[(long)b * 768 + c2] = sl;
        }
    } else {
        const float* xr = cvf + (long)b * 768;
        #pragma unroll
        for (int it = 0; it < 3; ++it) xs[tid + it * 256] = xr[tid + it * 256];
    }
    __syncthreads();

    for (int c = tid; c < 384; c += 256) {
        const float* wr = W1 + (long)c * 768;
        float acc = 0.f;
        #pragma unroll 8
        for (int k = 0; k < 768; k += 4) {
            float4 xv = *(const float4*)&xs[k];
            float4 wv = *(const float4*)(wr + k);
            acc += xv.x * wv.x + xv.y * wv.y + xv.z * wv.z + xv.w * wv.w;
        }
        hs[c] = fmaxf(acc + b1[c], 0.f);
    }
    __syncthreads();

    int c = tid >> 3, g = tid & 7;
    float acc = 0.f;
    if (c < OP_) {
        const float* wr = W2 + (long)c * HH_;
        #pragma unroll
        for (int t = 0; t < 12; ++t) {
            int k = (g + 8 * t) * 4;
            float4 xv = *(const float4*)&hs[k];
            float4 wv = *(const float4*)(wr + k);
            acc += xv.x * wv.x + xv.y * wv.y + xv.z * wv.z + xv.w * wv.w;
        }
    }
    acc += __shfl_xor(acc, 1);
    acc += __shfl_xor(acc, 2);
    acc += __shfl_xor(acc, 4);
    if (c < OP_ && g == 0)
        op_out[((long)b * E_ + i) * OP_ + c] = acc + b2[c];
}

// ---------------------------------------------------------------------------
// Fused od head with og-gates-L1 prologue.
// ---------------------------------------------------------------------------
__global__ __launch_bounds__(256) void k_odhead(
    const float* __restrict__ GI,
    const float* __restrict__ bihg, const float* __restrict__ bhhg,
    const float* __restrict__ hp, long ldhp,
    float* __restrict__ hx1f, short* __restrict__ hx1hi, short* __restrict__ hx1lo,
    const float* __restrict__ W1, const float* __restrict__ b1,
    const float* __restrict__ W2, const float* __restrict__ b2,
    float* __restrict__ od_base, long ldl,
    float* __restrict__ prev, int i,
    const float* __restrict__ pcb, const float* __restrict__ pnb,
    short* __restrict__ pvhi, short* __restrict__ pvlo,
    int do_final)
{
    int b = blockIdx.x, tid = threadIdx.x;
    __shared__ float xs[768];
    __shared__ float ps[768];
    __shared__ float hidL[24];
    __shared__ float lg[48];
    __shared__ float red[256];
    __shared__ int s_oidx;

    {
        const float* gb = GI + (long)b * 4608;
        #pragma unroll
        for (int it = 0; it < 3; ++it) {
            int c2 = tid + it * 256;
            float ir  = gb[c2]        + bihg[c2];
            float iz  = gb[768 + c2]  + bihg[768 + c2];
            float in_ = gb[1536 + c2] + bihg[1536 + c2];
            float hr  = gb[2304 + c2] + bhhg[c2];
            float hz  = gb[3072 + c2] + bhhg[768 + c2];
            float hn  = gb[3840 + c2] + bhhg[1536 + c2];
            float r  = 1.f / (1.f + expf(-(ir + hr)));
            float z_ = 1.f / (1.f + expf(-(iz + hz)));
            float n  = tanhf(in_ + r * hn);
            float hpv = hp[(long)b * ldhp + c2];
            float v = (1.f - z_) * n + z_ * hpv;
            xs[c2] = v;
            hx1f[(long)b * 768 + c2] = v;
            short sh, sl; split1(v, sh, sl);
            hx1hi[(long)b * 768 + c2] = sh;
            hx1lo[(long)b * 768 + c2] = sl;
        }
    }
    __syncthreads();

    int c = tid >> 3, g = tid & 7;
    float acc = 0.f;
    if (c < 24) {
        const float* wr = W1 + (long)c * 768;
        #pragma unroll
        for (int t = 0; t < 24; ++t) {
            int k = (g + 8 * t) * 4;
            float4 xv = *(const float4*)&xs[k];
            float4 wv = *(const float4*)(wr + k);
            acc += xv.x * wv.x + xv.y * wv.y + xv.z * wv.z + xv.w * wv.w;
        }
    }
    acc += __shfl_xor(acc, 1);
    acc += __shfl_xor(acc, 2);
    acc += __shfl_xor(acc, 4);
    if (c < 24 && g == 0) hidL[c] = fmaxf(acc + b1[c], 0.f);
    __syncthreads();

    if (tid < 48) {
        float a2 = b2[tid];
        const float* w2 = W2 + tid * 24;
        #pragma unroll
        for (int k = 0; k < 24; ++k) a2 += hidL[k] * w2[k];
        lg[tid] = a2;
        od_base[(long)b * ldl + tid] = a2;
    }

    long poff = ((long)b * E_ + i) * 768;
    float* prow = prev + poff;
    float m = -3.4e38f;
    #pragma unroll
    for (int it = 0; it < 3; ++it) m = fmaxf(m, prow[tid + it * 256]);
    red[tid] = m; __syncthreads();
    for (int o = 128; o > 0; o >>= 1) { if (tid < o) red[tid] = fmaxf(red[tid], red[tid + o]); __syncthreads(); }
    float m0 = red[0];

    if (tid == 0) {      // first-max tie semantics (matches jnp.argmax)
        float best = lg[0]; int bi = 0;
        for (int k2 = 1; k2 < K_; ++k2) { float v = lg[k2]; if (v > best) { best = v; bi = k2; } }
        s_oidx = bi;
    }
    __syncthreads();
    int oidx = s_oidx;
    bool empty0 = (m0 == 0.0f);
    bool cond = (oidx == 0) && empty0;
    if (cond) {
        #pragma unroll
        for (int it = 0; it < 3; ++it) {
            int c2 = tid + it * 256;
            float v = xs[c2];
            prow[c2] = v;
            short sh, sl; split1(v, sh, sl);
            pvhi[poff + c2] = sh; pvlo[poff + c2] = sl;
        }
    }
    __syncthreads();

    if (!do_final) return;

    float mfin;
    if (cond) {
        float mx = -3.4e38f;
        #pragma unroll
        for (int it = 0; it < 3; ++it) mx = fmaxf(mx, xs[tid + it * 256]);
        red[tid] = mx; __syncthreads();
        for (int o = 128; o > 0; o >>= 1) { if (tid < o) red[tid] = fmaxf(red[tid], red[tid + o]); __syncthreads(); }
        mfin = red[0];
    } else {
        mfin = m0;
    }

    const float* src;
    if (oidx < C_)            src = pcb + (long)oidx * 768;
    else if (oidx < C_ + M_)  src = pnb + ((long)b * M_ + (oidx - C_)) * 768;
    else                      src = prev + ((long)b * E_ + (oidx - C_ - M_)) * 768;
    #pragma unroll
    for (int it = 0; it < 3; ++it) ps[tid + it * 256] = src[tid + it * 256];
    __syncthreads();

    if (mfin == 0.0f) {
        #pragma unroll
        for (int it = 0; it < 3; ++it) {
            int c2 = tid + it * 256;
            float v = ps[c2];
            prow[c2] = v;
            short sh, sl; split1(v, sh, sl);
            pvhi[poff + c2] = sh; pvlo[poff + c2] = sl;
        }
    }
}

// Build num_vec: for (b,m) find first/last position with number_mask==m+1
__global__ void k_numvec(const float* __restrict__ inp, const int* __restrict__ nmask,
                         float* __restrict__ numvec)
{
    int b = blockIdx.x / M_, m = blockIdx.x % M_;
    int tid = threadIdx.x;
    int fmin = S_, lmax = -1;
    for (int s = tid; s < S_; s += 256) {
        if (nmask[b * S_ + s] == m + 1) {
            if (s < fmin) fmin = s;
            if (s > lmax) lmax = s;
        }
    }
    __shared__ int sf[256], sl[256];
    sf[tid] = fmin; sl[tid] = lmax; __syncthreads();
    for (int o = 128; o > 0; o >>= 1) {
        if (tid < o) {
            sf[tid] = min(sf[tid], sf[tid + o]);
            sl[tid] = max(sl[tid], sl[tid + o]);
        }
        __syncthreads();
    }
    int first = sf[0], last = sl[0];
    bool exists = (last >= 0);
    if (!exists) { first = 0; last = 0; }
    const float* fv = inp + ((long)b * S_ + first) * H_;
    const float* lv = inp + ((long)b * S_ + last) * H_;
    float* dst = numvec + ((long)b * M_ + m) * H2_;
    for (int h = tid; h < H_; h += 256) {
        dst[h]      = exists ? fv[h] : 0.f;
        dst[H_ + h] = exists ? lv[h] : 0.f;
    }
}

__global__ void k_copy_cv(const float* __restrict__ inp, float* __restrict__ cvv,
                          short* __restrict__ cvhi, short* __restrict__ cvlo)
{
    int b = blockIdx.x;
    for (int h = threadIdx.x; h < H_; h += 256) {
        float v = inp[(long)b * S_ * H_ + h];
        cvv[b * H_ + h] = v;
        short sh, sl; split1(v, sh, sl);
        cvhi[b * H_ + h] = sh; cvlo[b * H_ + h] = sl;
    }
}

// ---------------------------------------------------------------------------
extern "C" void kernel_launch(void* const* d_in, const int* in_sizes, int n_in,
                              void* d_out, int out_size, void* d_ws, size_t ws_size,
                              hipStream_t stream)
{
    const float* inp    = (const float*)d_in[0];
    const int*   nmask  = (const int*)  d_in[3];
    const int*   gops   = (const int*)  d_in[4];
    const int*   gopd   = (const int*)  d_in[5];
    const float* constv = (const float*)d_in[6];
    const float* opv    = (const float*)d_in[7];
    const float* opj_W  = (const float*)d_in[8];
    const float* opj_b  = (const float*)d_in[9];
    const float* opj_g  = (const float*)d_in[10];
    const float* opj_be = (const float*)d_in[11];
    const float* odj_W  = (const float*)d_in[12];
    const float* odj_b  = (const float*)d_in[13];
    const float* odj_g  = (const float*)d_in[14];
    const float* odj_be = (const float*)d_in[15];
    const float* opc_W1 = (const float*)d_in[16];
    const float* opc_b1 = (const float*)d_in[17];
    const float* opc_W2 = (const float*)d_in[18];
    const float* opc_b2 = (const float*)d_in[19];
    const float* odc_W1 = (const float*)d_in[20];
    const float* odc_b1 = (const float*)d_in[21];
    const float* odc_W2 = (const float*)d_in[22];
    const float* odc_b2 = (const float*)d_in[23];
    const float* og_Wih = (const float*)d_in[24];
    const float* og_Whh = (const float*)d_in[25];
    const float* og_bih = (const float*)d_in[26];
    const float* og_bhh = (const float*)d_in[27];
    const float* cg_Wih = (const float*)d_in[28];
    const float* cg_Whh = (const float*)d_in[29];
    const float* cg_bih = (const float*)d_in[30];
    const float* cg_bhh = (const float*)d_in[31];

    float* op_out = (float*)d_out;                  // (B, E, OP)
    float* od_out = op_out + (long)B_ * E_ * OP_;   // (B, E, A, K)

    // ---- workspace partition ----
    float* ws      = (float*)d_ws;
    float* num_vec = ws; ws += (long)B_ * M_ * H2_;       // 1024x1536
    float* pn      = ws; ws += (long)B_ * M_ * H_;        // 1024x768
    float* pcb     = ws; ws += (long)64 * H_;             // 24 used (pad 64)
    float* gopv    = ws; ws += (long)B_ * E_ * H_;        // 512x768
    float* prev    = ws; ws += (long)B_ * E_ * H_;
    float* gigh    = ws; ws += (long)B_ * 4608;           // gi | gh
    float* cv      = ws; ws += (long)B_ * H_;
    float* h0      = ws; ws += (long)B_ * H_;
    float* hx0     = ws; ws += (long)B_ * H_;
    float* hx1     = ws; ws += (long)B_ * H_;

    // bf16 hi/lo shadows (shorts; all sizes even)
    auto alloc_s = [&](long elems) -> short* {
        short* p = (short*)ws; ws += elems / 2; return p;
    };
    const long nOG = (long)2 * G3_ * H_;   // per GRU stack (2 layers)
    short* og_ih_hi = alloc_s(nOG); short* og_ih_lo = alloc_s(nOG);
    short* og_hh_hi = alloc_s(nOG); short* og_hh_lo = alloc_s(nOG);
    short* cg_ih_hi = alloc_s(nOG); short* cg_ih_lo = alloc_s(nOG);
    short* cg_hh_hi = alloc_s(nOG); short* cg_hh_lo = alloc_s(nOG);
    const long nPJ = (long)H_ * H2_;
    short* odj_hi = alloc_s(nPJ); short* odj_lo = alloc_s(nPJ);
    short* opj_hi = alloc_s(nPJ); short* opj_lo = alloc_s(nPJ);
    short* pn_hi  = alloc_s((long)B_ * M_ * H_); short* pn_lo  = alloc_s((long)B_ * M_ * H_);
    short* pc_hi  = alloc_s((long)64 * H_);      short* pc_lo  = alloc_s((long)64 * H_);
    short* gv_hi  = alloc_s((long)B_ * E_ * H_); short* gv_lo  = alloc_s((long)B_ * E_ * H_);
    short* pv_hi  = alloc_s((long)B_ * E_ * H_); short* pv_lo  = alloc_s((long)B_ * E_ * H_);
    short* cv_hi  = alloc_s((long)B_ * H_);      short* cv_lo  = alloc_s((long)B_ * H_);
    short* h0_hi  = alloc_s((long)B_ * H_);      short* h0_lo  = alloc_s((long)B_ * H_);
    short* hx0_hi = alloc_s((long)B_ * H_);      short* hx0_lo = alloc_s((long)B_ * H_);
    short* hx1_hi = alloc_s((long)B_ * H_);      short* hx1_lo = alloc_s((long)B_ * H_);

    hipMemsetAsync(prev, 0, (size_t)B_ * E_ * H_ * sizeof(float), stream);
    hipMemsetAsync(pv_hi, 0, (size_t)2 * B_ * E_ * H_ * sizeof(short), stream);

    // ---- weight pre-split ----
    auto split = [&](const float* src, short* hi, short* lo, long n) {
        int n4 = (int)(n / 4);
        k_split4<<<(n4 + 255) / 256, 256, 0, stream>>>(src, hi, lo, n4);
    };
    split(og_Wih, og_ih_hi, og_ih_lo, nOG);
    split(og_Whh, og_hh_hi, og_hh_lo, nOG);
    split(cg_Wih, cg_ih_hi, cg_ih_lo, nOG);
    split(cg_Whh, cg_hh_hi, cg_hh_lo, nOG);
    split(odj_W,  odj_hi,  odj_lo,  nPJ);
    split(opj_W,  opj_hi,  opj_lo,  nPJ);

    // ---- preprocessing ----
    k_numvec<<<B_ * M_, 256, 0, stream>>>(inp, nmask, num_vec);

    k_proj_mfma<<<dim3(12, 16), 256, 0, stream>>>(num_vec, H2_, nullptr, 1024,
                                                  odj_hi, odj_lo, H2_, pn, H_);
    k_ln2<<<1024, 256, 0, stream>>>(pn, odj_b, odj_g, odj_be, pn_hi, pn_lo);

    k_proj_mfma<<<dim3(12, 1), 256, 0, stream>>>(constv, H2_, nullptr, C_,
                                                 odj_hi, odj_lo, H2_, pcb, H_);
    k_ln2<<<C_, 256, 0, stream>>>(pcb, odj_b, odj_g, odj_be, pc_hi, pc_lo);

    k_proj_mfma<<<dim3(12, 8), 256, 0, stream>>>(opv, H2_, gops, 512,
                                                 opj_hi, opj_lo, H2_, gopv, H_);
    k_ln2<<<512, 256, 0, stream>>>(gopv, opj_b, opj_g, opj_be, gv_hi, gv_lo);

    k_copy_cv<<<B_, 256, 0, stream>>>(inp, cv, cv_hi, cv_lo);

    // ---- decode loop ----
    const long ldE = (long)E_ * H_;
    const long lW  = (long)G3_ * H_;   // layer-1 weight offset

    for (int i = 0; i < E_; ++i) {
        if (i > 0) {
            const float* hrow = prev + (long)(i - 1) * H_;
            const short* hrhi = pv_hi + (long)(i - 1) * H_;
            const short* hrlo = pv_lo + (long)(i - 1) * H_;
            k_gru_mfma<<<288, 256, 0, stream>>>(cv_hi, cv_lo, H_, 0, nullptr, 0, 0,
                                                nullptr, nullptr, nullptr, nullptr, nullptr, nullptr,
                                                hrhi, hrlo, ldE,
                                                cg_ih_hi, cg_ih_lo, cg_hh_hi, cg_hh_lo, gigh);
            k_gates2<<<192, 256, 0, stream>>>(gigh, hrow, ldE, cg_bih, cg_bhh, h0, h0_hi, h0_lo);
            k_gru_mfma<<<288, 256, 0, stream>>>(h0_hi, h0_lo, H_, 0, nullptr, 0, 0,
                                                nullptr, nullptr, nullptr, nullptr, nullptr, nullptr,
                                                hrhi, hrlo, ldE,
                                                cg_ih_hi + lW, cg_ih_lo + lW,
                                                cg_hh_hi + lW, cg_hh_lo + lW, gigh);
            k_ophead_fused<<<B_, 256, 0, stream>>>(1, gigh, cg_bih + G3_, cg_bhh + G3_,
                                                   hrow, ldE, cv, cv_hi, cv_lo,
                                                   opc_W1, opc_b1, opc_W2, opc_b2, op_out, i);
        } else {
            k_ophead_fused<<<B_, 256, 0, stream>>>(0, gigh, cg_bih, cg_bhh,
                                                   cv, H_, cv, cv_hi, cv_lo,
                                                   opc_W1, opc_b1, opc_W2, opc_b2, op_out, i);
        }

        for (int j = 0; j < A_; ++j) {
            const short *xhi, *xlo; long ldx; int pickm;
            if (j == 0) { xhi = gv_hi + (long)i * H_; xlo = gv_lo + (long)i * H_; ldx = ldE; pickm = 0; }
            else        { xhi = nullptr; xlo = nullptr; ldx = 0; pickm = 1; }
            const float* hp0 = (j == 0) ? cv : hx0;
            const float* hp1 = (j == 0) ? cv : hx1;
            const short* hp0hi = (j == 0) ? cv_hi : hx0_hi;
            const short* hp0lo = (j == 0) ? cv_lo : hx0_lo;
            const short* hp1hi = (j == 0) ? cv_hi : hx1_hi;
            const short* hp1lo = (j == 0) ? cv_lo : hx1_lo;

            k_gru_mfma<<<288, 256, 0, stream>>>(xhi, xlo, ldx, pickm, gopd, i, j - 1,
                                                pc_hi, pc_lo, pn_hi, pn_lo, pv_hi, pv_lo,
                                                hp0hi, hp0lo, H_,
                                                og_ih_hi, og_ih_lo, og_hh_hi, og_hh_lo, gigh);
            k_gates2<<<192, 256, 0, stream>>>(gigh, hp0, H_, og_bih, og_bhh, hx0, hx0_hi, hx0_lo);
            k_gru_mfma<<<288, 256, 0, stream>>>(hx0_hi, hx0_lo, H_, 0, nullptr, 0, 0,
                                                nullptr, nullptr, nullptr, nullptr, nullptr, nullptr,
                                                hp1hi, hp1lo, H_,
                                                og_ih_hi + lW, og_ih_lo + lW,
                                                og_hh_hi + lW, og_hh_lo + lW, gigh);

            float* od_base = od_out + ((long)i * A_ + j) * K_;
            k_odhead<<<B_, 256, 0, stream>>>(gigh, og_bih + G3_, og_bhh + G3_,
                                             hp1, H_, hx1, hx1_hi, hx1_lo,
                                             odc_W1, odc_b1, odc_W2, odc_b2,
                                             od_base, (long)E_ * A_ * K_,
                                             prev, i, pcb, pn, pv_hi, pv_lo,
                                             (j == A_ - 1) ? 1 : 0);
        }
    }
}

// Round 14
// 1427.671 us; speedup vs baseline: 1.1732x; 1.1732x over previous
//
#include <hip/hip_runtime.h>
#include <math.h>

// Problem constants
constexpr int B_  = 64;
constexpr int S_  = 512;
constexpr int H_  = 768;
constexpr int H2_ = 1536;   // 2H
constexpr int G3_ = 2304;   // 3H
constexpr int OP_ = 18;
constexpr int C_  = 24;
constexpr int M_  = 16;
constexpr int E_  = 8;
constexpr int A_  = 3;
constexpr int K_  = 48;     // C+M+E
constexpr int HH_ = 384;    // H/2

using f32x4  = __attribute__((ext_vector_type(4))) float;
using short8 = __attribute__((ext_vector_type(8))) short;

#define MFMA16(a, b, c) __builtin_amdgcn_mfma_f32_16x16x32_bf16((a), (b), (c), 0, 0, 0)

// Split f32 into bf16 hi (truncate) + bf16 lo (residual, truncate).
__device__ __forceinline__ void split1(float x, short& h, short& l)
{
    union { float f; unsigned u; } a; a.f = x;
    h = (short)(a.u >> 16);
    union { unsigned u; float f; } hb; hb.u = a.u & 0xffff0000u;
    union { float f; unsigned u; } r; r.f = x - hb.f;
    l = (short)(r.u >> 16);
}

__device__ __forceinline__ void cvt8(float4 p0, float4 p1, short8& hi, short8& lo)
{
    float x[8] = {p0.x, p0.y, p0.z, p0.w, p1.x, p1.y, p1.z, p1.w};
    #pragma unroll
    for (int e = 0; e < 8; ++e) { short h, l; split1(x[e], h, l); hi[e] = h; lo[e] = l; }
}

// Bulk f32 -> bf16 hi/lo splitter (weights, once per launch)
__global__ void k_split4(const float* __restrict__ src, short* __restrict__ hi,
                         short* __restrict__ lo, int n4)
{
    int t = blockIdx.x * 256 + threadIdx.x;
    if (t >= n4) return;
    float4 v = ((const float4*)src)[t];
    float x[4] = {v.x, v.y, v.z, v.w};
    short h[4], l[4];
    #pragma unroll
    for (int e = 0; e < 4; ++e) split1(x[e], h[e], l[e]);
    ((short4*)hi)[t] = make_short4(h[0], h[1], h[2], h[3]);
    ((short4*)lo)[t] = make_short4(l[0], l[1], l[2], l[3]);
}

// ---------------------------------------------------------------------------
// GRU dual GEMM via MFMA: grid(144) x 512 thr (8 waves), 32-col tiles.
// bx<72: gi cols = x @ Wih^T; else gh. Waves split K=768 EIGHT ways
// (3 k-tiles each), in-register accum, LDS reduce (7 writers), wave0
// stores f32 to gigh.
// vs R12 (4 waves): same blocks/tiles/traffic, 2x waves/SIMD -> per-wave
// exposed load latency halves. K-grouping 8-way (absmax may shift ~ulp).
// ---------------------------------------------------------------------------
__global__ __launch_bounds__(512) void k_gru_mfma(
    const short* __restrict__ xhi, const short* __restrict__ xlo, long ldx, int pickmode,
    const int* __restrict__ gopd, int i, int jm1,
    const short* __restrict__ pchi, const short* __restrict__ pclo,
    const short* __restrict__ pnhi, const short* __restrict__ pnlo,
    const short* __restrict__ pvhi, const short* __restrict__ pvlo,
    const short* __restrict__ hhi, const short* __restrict__ hlo, long ldh,
    const short* __restrict__ Wih_hi, const short* __restrict__ Wih_lo,
    const short* __restrict__ Whh_hi, const short* __restrict__ Whh_lo,
    float* __restrict__ C)
{
    const int tid  = threadIdx.x;
    const int lane = tid & 63;
    const int w    = tid >> 6;          // 0..7
    const int bx   = blockIdx.x;
    const bool hside = bx >= 72;
    const int n0 = (hside ? bx - 72 : bx) * 32;
    const int koff = (lane >> 4) * 8;

    const short* ahi[4]; const short* alo[4];
    #pragma unroll
    for (int rt = 0; rt < 4; ++rt) {
        int r = rt * 16 + (lane & 15);
        long off;
        const short *bh_, *bl_;
        if (hside) { bh_ = hhi; bl_ = hlo; off = (long)r * ldh; }
        else if (!pickmode) { bh_ = xhi; bl_ = xlo; off = (long)r * ldx; }
        else {
            int idx = gopd[(r * E_ + i) * A_ + jm1];
            if (idx < C_)           { bh_ = pchi; bl_ = pclo; off = (long)idx * H_; }
            else if (idx < C_ + M_) { bh_ = pnhi; bl_ = pnlo; off = ((long)r * M_ + (idx - C_)) * H_; }
            else                    { bh_ = pvhi; bl_ = pvlo; off = ((long)r * E_ + (idx - C_ - M_)) * H_; }
        }
        ahi[rt] = bh_ + off + koff;
        alo[rt] = bl_ + off + koff;
    }
    const short* whi[2]; const short* wlo[2];
    const short* WH = hside ? Whh_hi : Wih_hi;
    const short* WL = hside ? Whh_lo : Wih_lo;
    #pragma unroll
    for (int nt = 0; nt < 2; ++nt) {
        long off = (long)(n0 + nt * 16 + (lane & 15)) * H_ + koff;
        whi[nt] = WH + off;
        wlo[nt] = WL + off;
    }

    f32x4 acc[4][2];
    #pragma unroll
    for (int rt = 0; rt < 4; ++rt)
        #pragma unroll
        for (int nt = 0; nt < 2; ++nt) acc[rt][nt] = (f32x4){0.f, 0.f, 0.f, 0.f};

    for (int kt = w * 3; kt < w * 3 + 3; ++kt) {
        const int kb = kt * 32;
        short8 Ah[4], Al[4];
        #pragma unroll
        for (int rt = 0; rt < 4; ++rt) {
            Ah[rt] = *(const short8*)(ahi[rt] + kb);
            Al[rt] = *(const short8*)(alo[rt] + kb);
        }
        #pragma unroll
        for (int nt = 0; nt < 2; ++nt) {
            short8 Bh = *(const short8*)(whi[nt] + kb);
            short8 Bl = *(const short8*)(wlo[nt] + kb);
            #pragma unroll
            for (int rt = 0; rt < 4; ++rt) {
                acc[rt][nt] = MFMA16(Ah[rt], Bh, acc[rt][nt]);
                acc[rt][nt] = MFMA16(Ah[rt], Bl, acc[rt][nt]);
                acc[rt][nt] = MFMA16(Al[rt], Bh, acc[rt][nt]);
            }
        }
    }

    __shared__ f32x4 Lr[56][64];        // 7 writer-waves x 8 frags
    if (w > 0) {
        #pragma unroll
        for (int rt = 0; rt < 4; ++rt)
            #pragma unroll
            for (int nt = 0; nt < 2; ++nt)
                Lr[(w - 1) * 8 + rt * 2 + nt][lane] = acc[rt][nt];
    }
    __syncthreads();
    if (w == 0) {
        float* Cb = C + (hside ? 2304 : 0) + n0;
        #pragma unroll
        for (int rt = 0; rt < 4; ++rt)
            #pragma unroll
            for (int nt = 0; nt < 2; ++nt) {
                int f = rt * 2 + nt;
                f32x4 s = acc[rt][nt];
                #pragma unroll
                for (int q = 0; q < 7; ++q) s = s + Lr[q * 8 + f][lane];
                int col = nt * 16 + (lane & 15);
                int rb  = rt * 16 + ((lane >> 4) << 2);
                #pragma unroll
                for (int r = 0; r < 4; ++r)
                    Cb[(long)(rb + r) * 4608 + col] = s[r];
            }
    }
}

// ---------------------------------------------------------------------------
// Projection GEMM: A f32 (cvt in-reg, runs once), W pre-split bf16.
// ---------------------------------------------------------------------------
__global__ __launch_bounds__(256) void k_proj_mfma(
    const float* __restrict__ Ab, long lda, const int* __restrict__ gidx, int Mm,
    const short* __restrict__ Whi, const short* __restrict__ Wlo, int wld,
    float* __restrict__ C, int ldc)
{
    const int tid  = threadIdx.x;
    const int lane = tid & 63;
    const int w    = tid >> 6;
    const int n0 = blockIdx.x * 64;
    const int r0 = blockIdx.y * 64;
    const int koff = (lane >> 4) * 8;

    const float* arow[4];
    #pragma unroll
    for (int rt = 0; rt < 4; ++rt) {
        int r = r0 + rt * 16 + (lane & 15);
        int rr = r < Mm ? r : (Mm - 1);
        const float* s = gidx ? (Ab + (long)gidx[rr] * lda) : (Ab + (long)rr * lda);
        arow[rt] = s + koff;
    }
    const short* whi[4]; const short* wlo[4];
    #pragma unroll
    for (int nt = 0; nt < 4; ++nt) {
        long off = (long)(n0 + nt * 16 + (lane & 15)) * wld + koff;
        whi[nt] = Whi + off; wlo[nt] = Wlo + off;
    }

    f32x4 acc[4][4];
    #pragma unroll
    for (int rt = 0; rt < 4; ++rt)
        #pragma unroll
        for (int nt = 0; nt < 4; ++nt) acc[rt][nt] = (f32x4){0.f, 0.f, 0.f, 0.f};

    for (int kt = w * 12; kt < w * 12 + 12; ++kt) {
        const int kb = kt * 32;
        short8 ah[4], al[4];
        #pragma unroll
        for (int rt = 0; rt < 4; ++rt) {
            float4 p0 = *(const float4*)(arow[rt] + kb);
            float4 p1 = *(const float4*)(arow[rt] + kb + 4);
            cvt8(p0, p1, ah[rt], al[rt]);
        }
        #pragma unroll
        for (int nt = 0; nt < 4; ++nt) {
            short8 Bh = *(const short8*)(whi[nt] + kb);
            short8 Bl = *(const short8*)(wlo[nt] + kb);
            #pragma unroll
            for (int rt = 0; rt < 4; ++rt) {
                acc[rt][nt] = MFMA16(ah[rt], Bh, acc[rt][nt]);
                acc[rt][nt] = MFMA16(ah[rt], Bl, acc[rt][nt]);
                acc[rt][nt] = MFMA16(al[rt], Bh, acc[rt][nt]);
            }
        }
    }

    __shared__ f32x4 Lr[48][64];
    if (w > 0) {
        #pragma unroll
        for (int rt = 0; rt < 4; ++rt)
            #pragma unroll
            for (int nt = 0; nt < 4; ++nt)
                Lr[(w - 1) * 16 + rt * 4 + nt][lane] = acc[rt][nt];
    }
    __syncthreads();
    if (w == 0) {
        #pragma unroll
        for (int rt = 0; rt < 4; ++rt)
            #pragma unroll
            for (int nt = 0; nt < 4; ++nt) {
                int f = rt * 4 + nt;
                f32x4 s = acc[rt][nt];
                s = s + Lr[f][lane] + Lr[16 + f][lane] + Lr[32 + f][lane];
                int col = n0 + nt * 16 + (lane & 15);
                int rb  = r0 + rt * 16 + ((lane >> 4) << 2);
                #pragma unroll
                for (int r = 0; r < 4; ++r)
                    if (rb + r < Mm) C[(long)(rb + r) * ldc + col] = s[r];
            }
    }
}

// Gates (layer-0): read gi|gh, biases, hnew = (1-z)*n + z*h (+ shadow)
__global__ void k_gates2(const float* __restrict__ GI,
                         const float* __restrict__ h, long ldh,
                         const float* __restrict__ bih, const float* __restrict__ bhh,
                         float* __restrict__ hnew,
                         short* __restrict__ hnhi, short* __restrict__ hnlo)
{
    int t = blockIdx.x * 256 + threadIdx.x;       // 64*768
    int b = t / 768, c = t - b * 768;
    const float* gb = GI + (long)b * 4608;
    float ir  = gb[c]        + bih[c];
    float iz  = gb[768 + c]  + bih[768 + c];
    float in_ = gb[1536 + c] + bih[1536 + c];
    float hr  = gb[2304 + c] + bhh[c];
    float hz  = gb[3072 + c] + bhh[768 + c];
    float hn  = gb[3840 + c] + bhh[1536 + c];
    float r  = 1.f / (1.f + expf(-(ir + hr)));
    float z_ = 1.f / (1.f + expf(-(iz + hz)));
    float n  = tanhf(in_ + r * hn);
    float hp = h[(long)b * ldh + c];
    float v = (1.f - z_) * n + z_ * hp;
    hnew[t] = v;
    short sh, sl; split1(v, sh, sl);
    hnhi[t] = sh; hnlo[t] = sl;
}

// Add bias then LayerNorm each 768-wide row of X in place (+ shadow).
__global__ void k_ln2(float* __restrict__ X, const float* __restrict__ bias,
                      const float* __restrict__ g, const float* __restrict__ be,
                      short* __restrict__ Xhi, short* __restrict__ Xlo)
{
    int row = blockIdx.x, tid = threadIdx.x;
    __shared__ float red[256];
    float* xr = X + (long)row * 768;
    float v[3];
    #pragma unroll
    for (int it = 0; it < 3; ++it) {
        int c2 = tid + it * 256;
        v[it] = xr[c2] + bias[c2];
    }
    float s = v[0] + v[1] + v[2];
    red[tid] = s; __syncthreads();
    for (int o = 128; o > 0; o >>= 1) { if (tid < o) red[tid] += red[tid + o]; __syncthreads(); }
    float mu = red[0] / 768.f;
    __syncthreads();
    float vv = 0.f;
    #pragma unroll
    for (int it = 0; it < 3; ++it) { float d = v[it] - mu; vv += d * d; }
    red[tid] = vv; __syncthreads();
    for (int o = 128; o > 0; o >>= 1) { if (tid < o) red[tid] += red[tid + o]; __syncthreads(); }
    float inv = 1.f / sqrtf(red[0] / 768.f + 1e-5f);
    #pragma unroll
    for (int it = 0; it < 3; ++it) {
        int c2 = tid + it * 256;
        float o2 = (v[it] - mu) * inv * g[c2] + be[c2];
        xr[c2] = o2;
        short sh, sl; split1(o2, sh, sl);
        Xhi[(long)row * 768 + c2] = sh;
        Xlo[(long)row * 768 + c2] = sl;
    }
}

// ---------------------------------------------------------------------------
// Fused op head with optional cg-gates-L1 prologue (do_gates).
// ---------------------------------------------------------------------------
__global__ __launch_bounds__(256) void k_ophead_fused(
    int do_gates,
    const float* __restrict__ GI,
    const float* __restrict__ bihg, const float* __restrict__ bhhg,
    const float* __restrict__ hp, long ldhp,
    float* __restrict__ cvf, short* __restrict__ cvhi, short* __restrict__ cvlo,
    const float* __restrict__ W1, const float* __restrict__ b1,
    const float* __restrict__ W2, const float* __restrict__ b2,
    float* __restrict__ op_out, int i)
{
    int b = blockIdx.x, tid = threadIdx.x;
    __shared__ float xs[768];
    __shared__ float hs[384];

    if (do_gates) {
        const float* gb = GI + (long)b * 4608;
        #pragma unroll
        for (int it = 0; it < 3; ++it) {
            int c2 = tid + it * 256;
            float ir  = gb[c2]        + bihg[c2];
            float iz  = gb[768 + c2]  + bihg[768 + c2];
            float in_ = gb[1536 + c2] + bihg[1536 + c2];
            float hr  = gb[2304 + c2] + bhhg[c2];
            float hz  = gb[3072 + c2] + bhhg[768 + c2];
            float hn  = gb[3840 + c2] + bhhg[1536 + c2];
            float r  = 1.f / (1.f + expf(-(ir + hr)));
            float z_ = 1.f / (1.f + expf(-(iz + hz)));
            float n  = tanhf(in_ + r * hn);
            float hpv = hp[(long)b * ldhp + c2];
            float v = (1.f - z_) * n + z_ * hpv;
            xs[c2] = v;
            cvf[(long)b * 768 + c2] = v;
            short sh, sl; split1(v, sh, sl);
            cvhi[(long)b * 768 + c2] = sh;
            cvlo[(long)b * 768 + c2] = sl;
        }
    } else {
        const float* xr = cvf + (long)b * 768;
        #pragma unroll
        for (int it = 0; it < 3; ++it) xs[tid + it * 256] = xr[tid + it * 256];
    }
    __syncthreads();

    for (int c = tid; c < 384; c += 256) {
        const float* wr = W1 + (long)c * 768;
        float acc = 0.f;
        #pragma unroll 8
        for (int k = 0; k < 768; k += 4) {
            float4 xv = *(const float4*)&xs[k];
            float4 wv = *(const float4*)(wr + k);
            acc += xv.x * wv.x + xv.y * wv.y + xv.z * wv.z + xv.w * wv.w;
        }
        hs[c] = fmaxf(acc + b1[c], 0.f);
    }
    __syncthreads();

    int c = tid >> 3, g = tid & 7;
    float acc = 0.f;
    if (c < OP_) {
        const float* wr = W2 + (long)c * HH_;
        #pragma unroll
        for (int t = 0; t < 12; ++t) {
            int k = (g + 8 * t) * 4;
            float4 xv = *(const float4*)&hs[k];
            float4 wv = *(const float4*)(wr + k);
            acc += xv.x * wv.x + xv.y * wv.y + xv.z * wv.z + xv.w * wv.w;
        }
    }
    acc += __shfl_xor(acc, 1);
    acc += __shfl_xor(acc, 2);
    acc += __shfl_xor(acc, 4);
    if (c < OP_ && g == 0)
        op_out[((long)b * E_ + i) * OP_ + c] = acc + b2[c];
}

// ---------------------------------------------------------------------------
// Fused od head with og-gates-L1 prologue.
// ---------------------------------------------------------------------------
__global__ __launch_bounds__(256) void k_odhead(
    const float* __restrict__ GI,
    const float* __restrict__ bihg, const float* __restrict__ bhhg,
    const float* __restrict__ hp, long ldhp,
    float* __restrict__ hx1f, short* __restrict__ hx1hi, short* __restrict__ hx1lo,
    const float* __restrict__ W1, const float* __restrict__ b1,
    const float* __restrict__ W2, const float* __restrict__ b2,
    float* __restrict__ od_base, long ldl,
    float* __restrict__ prev, int i,
    const float* __restrict__ pcb, const float* __restrict__ pnb,
    short* __restrict__ pvhi, short* __restrict__ pvlo,
    int do_final)
{
    int b = blockIdx.x, tid = threadIdx.x;
    __shared__ float xs[768];
    __shared__ float ps[768];
    __shared__ float hidL[24];
    __shared__ float lg[48];
    __shared__ float red[256];
    __shared__ int s_oidx;

    {
        const float* gb = GI + (long)b * 4608;
        #pragma unroll
        for (int it = 0; it < 3; ++it) {
            int c2 = tid + it * 256;
            float ir  = gb[c2]        + bihg[c2];
            float iz  = gb[768 + c2]  + bihg[768 + c2];
            float in_ = gb[1536 + c2] + bihg[1536 + c2];
            float hr  = gb[2304 + c2] + bhhg[c2];
            float hz  = gb[3072 + c2] + bhhg[768 + c2];
            float hn  = gb[3840 + c2] + bhhg[1536 + c2];
            float r  = 1.f / (1.f + expf(-(ir + hr)));
            float z_ = 1.f / (1.f + expf(-(iz + hz)));
            float n  = tanhf(in_ + r * hn);
            float hpv = hp[(long)b * ldhp + c2];
            float v = (1.f - z_) * n + z_ * hpv;
            xs[c2] = v;
            hx1f[(long)b * 768 + c2] = v;
            short sh, sl; split1(v, sh, sl);
            hx1hi[(long)b * 768 + c2] = sh;
            hx1lo[(long)b * 768 + c2] = sl;
        }
    }
    __syncthreads();

    int c = tid >> 3, g = tid & 7;
    float acc = 0.f;
    if (c < 24) {
        const float* wr = W1 + (long)c * 768;
        #pragma unroll
        for (int t = 0; t < 24; ++t) {
            int k = (g + 8 * t) * 4;
            float4 xv = *(const float4*)&xs[k];
            float4 wv = *(const float4*)(wr + k);
            acc += xv.x * wv.x + xv.y * wv.y + xv.z * wv.z + xv.w * wv.w;
        }
    }
    acc += __shfl_xor(acc, 1);
    acc += __shfl_xor(acc, 2);
    acc += __shfl_xor(acc, 4);
    if (c < 24 && g == 0) hidL[c] = fmaxf(acc + b1[c], 0.f);
    __syncthreads();

    if (tid < 48) {
        float a2 = b2[tid];
        const float* w2 = W2 + tid * 24;
        #pragma unroll
        for (int k = 0; k < 24; ++k) a2 += hidL[k] * w2[k];
        lg[tid] = a2;
        od_base[(long)b * ldl + tid] = a2;
    }

    long poff = ((long)b * E_ + i) * 768;
    float* prow = prev + poff;
    float m = -3.4e38f;
    #pragma unroll
    for (int it = 0; it < 3; ++it) m = fmaxf(m, prow[tid + it * 256]);
    red[tid] = m; __syncthreads();
    for (int o = 128; o > 0; o >>= 1) { if (tid < o) red[tid] = fmaxf(red[tid], red[tid + o]); __syncthreads(); }
    float m0 = red[0];

    if (tid == 0) {      // first-max tie semantics (matches jnp.argmax)
        float best = lg[0]; int bi = 0;
        for (int k2 = 1; k2 < K_; ++k2) { float v = lg[k2]; if (v > best) { best = v; bi = k2; } }
        s_oidx = bi;
    }
    __syncthreads();
    int oidx = s_oidx;
    bool empty0 = (m0 == 0.0f);
    bool cond = (oidx == 0) && empty0;
    if (cond) {
        #pragma unroll
        for (int it = 0; it < 3; ++it) {
            int c2 = tid + it * 256;
            float v = xs[c2];
            prow[c2] = v;
            short sh, sl; split1(v, sh, sl);
            pvhi[poff + c2] = sh; pvlo[poff + c2] = sl;
        }
    }
    __syncthreads();

    if (!do_final) return;

    float mfin;
    if (cond) {
        float mx = -3.4e38f;
        #pragma unroll
        for (int it = 0; it < 3; ++it) mx = fmaxf(mx, xs[tid + it * 256]);
        red[tid] = mx; __syncthreads();
        for (int o = 128; o > 0; o >>= 1) { if (tid < o) red[tid] = fmaxf(red[tid], red[tid + o]); __syncthreads(); }
        mfin = red[0];
    } else {
        mfin = m0;
    }

    const float* src;
    if (oidx < C_)            src = pcb + (long)oidx * 768;
    else if (oidx < C_ + M_)  src = pnb + ((long)b * M_ + (oidx - C_)) * 768;
    else                      src = prev + ((long)b * E_ + (oidx - C_ - M_)) * 768;
    #pragma unroll
    for (int it = 0; it < 3; ++it) ps[tid + it * 256] = src[tid + it * 256];
    __syncthreads();

    if (mfin == 0.0f) {
        #pragma unroll
        for (int it = 0; it < 3; ++it) {
            int c2 = tid + it * 256;
            float v = ps[c2];
            prow[c2] = v;
            short sh, sl; split1(v, sh, sl);
            pvhi[poff + c2] = sh; pvlo[poff + c2] = sl;
        }
    }
}

// Build num_vec: for (b,m) find first/last position with number_mask==m+1
__global__ void k_numvec(const float* __restrict__ inp, const int* __restrict__ nmask,
                         float* __restrict__ numvec)
{
    int b = blockIdx.x / M_, m = blockIdx.x % M_;
    int tid = threadIdx.x;
    int fmin = S_, lmax = -1;
    for (int s = tid; s < S_; s += 256) {
        if (nmask[b * S_ + s] == m + 1) {
            if (s < fmin) fmin = s;
            if (s > lmax) lmax = s;
        }
    }
    __shared__ int sf[256], sl[256];
    sf[tid] = fmin; sl[tid] = lmax; __syncthreads();
    for (int o = 128; o > 0; o >>= 1) {
        if (tid < o) {
            sf[tid] = min(sf[tid], sf[tid + o]);
            sl[tid] = max(sl[tid], sl[tid + o]);
        }
        __syncthreads();
    }
    int first = sf[0], last = sl[0];
    bool exists = (last >= 0);
    if (!exists) { first = 0; last = 0; }
    const float* fv = inp + ((long)b * S_ + first) * H_;
    const float* lv = inp + ((long)b * S_ + last) * H_;
    float* dst = numvec + ((long)b * M_ + m) * H2_;
    for (int h = tid; h < H_; h += 256) {
        dst[h]      = exists ? fv[h] : 0.f;
        dst[H_ + h] = exists ? lv[h] : 0.f;
    }
}

__global__ void k_copy_cv(const float* __restrict__ inp, float* __restrict__ cvv,
                          short* __restrict__ cvhi, short* __restrict__ cvlo)
{
    int b = blockIdx.x;
    for (int h = threadIdx.x; h < H_; h += 256) {
        float v = inp[(long)b * S_ * H_ + h];
        cvv[b * H_ + h] = v;
        short sh, sl; split1(v, sh, sl);
        cvhi[b * H_ + h] = sh; cvlo[b * H_ + h] = sl;
    }
}

// ---------------------------------------------------------------------------
extern "C" void kernel_launch(void* const* d_in, const int* in_sizes, int n_in,
                              void* d_out, int out_size, void* d_ws, size_t ws_size,
                              hipStream_t stream)
{
    const float* inp    = (const float*)d_in[0];
    const int*   nmask  = (const int*)  d_in[3];
    const int*   gops   = (const int*)  d_in[4];
    const int*   gopd   = (const int*)  d_in[5];
    const float* constv = (const float*)d_in[6];
    const float* opv    = (const float*)d_in[7];
    const float* opj_W  = (const float*)d_in[8];
    const float* opj_b  = (const float*)d_in[9];
    const float* opj_g  = (const float*)d_in[10];
    const float* opj_be = (const float*)d_in[11];
    const float* odj_W  = (const float*)d_in[12];
    const float* odj_b  = (const float*)d_in[13];
    const float* odj_g  = (const float*)d_in[14];
    const float* odj_be = (const float*)d_in[15];
    const float* opc_W1 = (const float*)d_in[16];
    const float* opc_b1 = (const float*)d_in[17];
    const float* opc_W2 = (const float*)d_in[18];
    const float* opc_b2 = (const float*)d_in[19];
    const float* odc_W1 = (const float*)d_in[20];
    const float* odc_b1 = (const float*)d_in[21];
    const float* odc_W2 = (const float*)d_in[22];
    const float* odc_b2 = (const float*)d_in[23];
    const float* og_Wih = (const float*)d_in[24];
    const float* og_Whh = (const float*)d_in[25];
    const float* og_bih = (const float*)d_in[26];
    const float* og_bhh = (const float*)d_in[27];
    const float* cg_Wih = (const float*)d_in[28];
    const float* cg_Whh = (const float*)d_in[29];
    const float* cg_bih = (const float*)d_in[30];
    const float* cg_bhh = (const float*)d_in[31];

    float* op_out = (float*)d_out;                  // (B, E, OP)
    float* od_out = op_out + (long)B_ * E_ * OP_;   // (B, E, A, K)

    // ---- workspace partition ----
    float* ws      = (float*)d_ws;
    float* num_vec = ws; ws += (long)B_ * M_ * H2_;       // 1024x1536
    float* pn      = ws; ws += (long)B_ * M_ * H_;        // 1024x768
    float* pcb     = ws; ws += (long)64 * H_;             // 24 used (pad 64)
    float* gopv    = ws; ws += (long)B_ * E_ * H_;        // 512x768
    float* prev    = ws; ws += (long)B_ * E_ * H_;
    float* gigh    = ws; ws += (long)B_ * 4608;           // gi | gh
    float* cv      = ws; ws += (long)B_ * H_;
    float* h0      = ws; ws += (long)B_ * H_;
    float* hx0     = ws; ws += (long)B_ * H_;
    float* hx1     = ws; ws += (long)B_ * H_;

    // bf16 hi/lo shadows (shorts; all sizes even)
    auto alloc_s = [&](long elems) -> short* {
        short* p = (short*)ws; ws += elems / 2; return p;
    };
    const long nOG = (long)2 * G3_ * H_;   // per GRU stack (2 layers)
    short* og_ih_hi = alloc_s(nOG); short* og_ih_lo = alloc_s(nOG);
    short* og_hh_hi = alloc_s(nOG); short* og_hh_lo = alloc_s(nOG);
    short* cg_ih_hi = alloc_s(nOG); short* cg_ih_lo = alloc_s(nOG);
    short* cg_hh_hi = alloc_s(nOG); short* cg_hh_lo = alloc_s(nOG);
    const long nPJ = (long)H_ * H2_;
    short* odj_hi = alloc_s(nPJ); short* odj_lo = alloc_s(nPJ);
    short* opj_hi = alloc_s(nPJ); short* opj_lo = alloc_s(nPJ);
    short* pn_hi  = alloc_s((long)B_ * M_ * H_); short* pn_lo  = alloc_s((long)B_ * M_ * H_);
    short* pc_hi  = alloc_s((long)64 * H_);      short* pc_lo  = alloc_s((long)64 * H_);
    short* gv_hi  = alloc_s((long)B_ * E_ * H_); short* gv_lo  = alloc_s((long)B_ * E_ * H_);
    short* pv_hi  = alloc_s((long)B_ * E_ * H_); short* pv_lo  = alloc_s((long)B_ * E_ * H_);
    short* cv_hi  = alloc_s((long)B_ * H_);      short* cv_lo  = alloc_s((long)B_ * H_);
    short* h0_hi  = alloc_s((long)B_ * H_);      short* h0_lo  = alloc_s((long)B_ * H_);
    short* hx0_hi = alloc_s((long)B_ * H_);      short* hx0_lo = alloc_s((long)B_ * H_);
    short* hx1_hi = alloc_s((long)B_ * H_);      short* hx1_lo = alloc_s((long)B_ * H_);

    hipMemsetAsync(prev, 0, (size_t)B_ * E_ * H_ * sizeof(float), stream);
    hipMemsetAsync(pv_hi, 0, (size_t)2 * B_ * E_ * H_ * sizeof(short), stream);

    // ---- weight pre-split ----
    auto split = [&](const float* src, short* hi, short* lo, long n) {
        int n4 = (int)(n / 4);
        k_split4<<<(n4 + 255) / 256, 256, 0, stream>>>(src, hi, lo, n4);
    };
    split(og_Wih, og_ih_hi, og_ih_lo, nOG);
    split(og_Whh, og_hh_hi, og_hh_lo, nOG);
    split(cg_Wih, cg_ih_hi, cg_ih_lo, nOG);
    split(cg_Whh, cg_hh_hi, cg_hh_lo, nOG);
    split(odj_W,  odj_hi,  odj_lo,  nPJ);
    split(opj_W,  opj_hi,  opj_lo,  nPJ);

    // ---- preprocessing ----
    k_numvec<<<B_ * M_, 256, 0, stream>>>(inp, nmask, num_vec);

    k_proj_mfma<<<dim3(12, 16), 256, 0, stream>>>(num_vec, H2_, nullptr, 1024,
                                                  odj_hi, odj_lo, H2_, pn, H_);
    k_ln2<<<1024, 256, 0, stream>>>(pn, odj_b, odj_g, odj_be, pn_hi, pn_lo);

    k_proj_mfma<<<dim3(12, 1), 256, 0, stream>>>(constv, H2_, nullptr, C_,
                                                 odj_hi, odj_lo, H2_, pcb, H_);
    k_ln2<<<C_, 256, 0, stream>>>(pcb, odj_b, odj_g, odj_be, pc_hi, pc_lo);

    k_proj_mfma<<<dim3(12, 8), 256, 0, stream>>>(opv, H2_, gops, 512,
                                                 opj_hi, opj_lo, H2_, gopv, H_);
    k_ln2<<<512, 256, 0, stream>>>(gopv, opj_b, opj_g, opj_be, gv_hi, gv_lo);

    k_copy_cv<<<B_, 256, 0, stream>>>(inp, cv, cv_hi, cv_lo);

    // ---- decode loop ----
    const long ldE = (long)E_ * H_;
    const long lW  = (long)G3_ * H_;   // layer-1 weight offset

    for (int i = 0; i < E_; ++i) {
        if (i > 0) {
            const float* hrow = prev + (long)(i - 1) * H_;
            const short* hrhi = pv_hi + (long)(i - 1) * H_;
            const short* hrlo = pv_lo + (long)(i - 1) * H_;
            k_gru_mfma<<<144, 512, 0, stream>>>(cv_hi, cv_lo, H_, 0, nullptr, 0, 0,
                                                nullptr, nullptr, nullptr, nullptr, nullptr, nullptr,
                                                hrhi, hrlo, ldE,
                                                cg_ih_hi, cg_ih_lo, cg_hh_hi, cg_hh_lo, gigh);
            k_gates2<<<192, 256, 0, stream>>>(gigh, hrow, ldE, cg_bih, cg_bhh, h0, h0_hi, h0_lo);
            k_gru_mfma<<<144, 512, 0, stream>>>(h0_hi, h0_lo, H_, 0, nullptr, 0, 0,
                                                nullptr, nullptr, nullptr, nullptr, nullptr, nullptr,
                                                hrhi, hrlo, ldE,
                                                cg_ih_hi + lW, cg_ih_lo + lW,
                                                cg_hh_hi + lW, cg_hh_lo + lW, gigh);
            k_ophead_fused<<<B_, 256, 0, stream>>>(1, gigh, cg_bih + G3_, cg_bhh + G3_,
                                                   hrow, ldE, cv, cv_hi, cv_lo,
                                                   opc_W1, opc_b1, opc_W2, opc_b2, op_out, i);
        } else {
            k_ophead_fused<<<B_, 256, 0, stream>>>(0, gigh, cg_bih, cg_bhh,
                                                   cv, H_, cv, cv_hi, cv_lo,
                                                   opc_W1, opc_b1, opc_W2, opc_b2, op_out, i);
        }

        for (int j = 0; j < A_; ++j) {
            const short *xhi, *xlo; long ldx; int pickm;
            if (j == 0) { xhi = gv_hi + (long)i * H_; xlo = gv_lo + (long)i * H_; ldx = ldE; pickm = 0; }
            else        { xhi = nullptr; xlo = nullptr; ldx = 0; pickm = 1; }
            const float* hp0 = (j == 0) ? cv : hx0;
            const float* hp1 = (j == 0) ? cv : hx1;
            const short* hp0hi = (j == 0) ? cv_hi : hx0_hi;
            const short* hp0lo = (j == 0) ? cv_lo : hx0_lo;
            const short* hp1hi = (j == 0) ? cv_hi : hx1_hi;
            const short* hp1lo = (j == 0) ? cv_lo : hx1_lo;

            k_gru_mfma<<<144, 512, 0, stream>>>(xhi, xlo, ldx, pickm, gopd, i, j - 1,
                                                pc_hi, pc_lo, pn_hi, pn_lo, pv_hi, pv_lo,
                                                hp0hi, hp0lo, H_,
                                                og_ih_hi, og_ih_lo, og_hh_hi, og_hh_lo, gigh);
            k_gates2<<<192, 256, 0, stream>>>(gigh, hp0, H_, og_bih, og_bhh, hx0, hx0_hi, hx0_lo);
            k_gru_mfma<<<144, 512, 0, stream>>>(hx0_hi, hx0_lo, H_, 0, nullptr, 0, 0,
                                                nullptr, nullptr, nullptr, nullptr, nullptr, nullptr,
                                                hp1hi, hp1lo, H_,
                                                og_ih_hi + lW, og_ih_lo + lW,
                                                og_hh_hi + lW, og_hh_lo + lW, gigh);

            float* od_base = od_out + ((long)i * A_ + j) * K_;
            k_odhead<<<B_, 256, 0, stream>>>(gigh, og_bih + G3_, og_bhh + G3_,
                                             hp1, H_, hx1, hx1_hi, hx1_lo,
                                             odc_W1, odc_b1, odc_W2, odc_b2,
                                             od_base, (long)E_ * A_ * K_,
                                             prev, i, pcb, pn, pv_hi, pv_lo,
                                             (j == A_ - 1) ? 1 : 0);
        }
    }
}

// Round 15
// 1403.408 us; speedup vs baseline: 1.1935x; 1.0173x over previous
//
#include <hip/hip_runtime.h>
#include <math.h>

// Problem constants
constexpr int B_  = 64;
constexpr int S_  = 512;
constexpr int H_  = 768;
constexpr int H2_ = 1536;   // 2H
constexpr int G3_ = 2304;   // 3H
constexpr int OP_ = 18;
constexpr int C_  = 24;
constexpr int M_  = 16;
constexpr int E_  = 8;
constexpr int A_  = 3;
constexpr int K_  = 48;     // C+M+E
constexpr int HH_ = 384;    // H/2

using f32x4  = __attribute__((ext_vector_type(4))) float;
using short8 = __attribute__((ext_vector_type(8))) short;

#define MFMA16(a, b, c) __builtin_amdgcn_mfma_f32_16x16x32_bf16((a), (b), (c), 0, 0, 0)

// Split f32 into bf16 hi (truncate) + bf16 lo (residual, truncate).
__device__ __forceinline__ void split1(float x, short& h, short& l)
{
    union { float f; unsigned u; } a; a.f = x;
    h = (short)(a.u >> 16);
    union { unsigned u; float f; } hb; hb.u = a.u & 0xffff0000u;
    union { float f; unsigned u; } r; r.f = x - hb.f;
    l = (short)(r.u >> 16);
}

__device__ __forceinline__ void cvt8(float4 p0, float4 p1, short8& hi, short8& lo)
{
    float x[8] = {p0.x, p0.y, p0.z, p0.w, p1.x, p1.y, p1.z, p1.w};
    #pragma unroll
    for (int e = 0; e < 8; ++e) { short h, l; split1(x[e], h, l); hi[e] = h; lo[e] = l; }
}

// Single-dispatch bulk splitter over 6 weight regions (float4 units).
__global__ void k_split_all(
    const float* __restrict__ s0, short* __restrict__ h0, short* __restrict__ l0, int e0,
    const float* __restrict__ s1, short* __restrict__ h1, short* __restrict__ l1, int e1,
    const float* __restrict__ s2, short* __restrict__ h2, short* __restrict__ l2, int e2,
    const float* __restrict__ s3, short* __restrict__ h3, short* __restrict__ l3, int e3,
    const float* __restrict__ s4, short* __restrict__ h4, short* __restrict__ l4, int e4,
    const float* __restrict__ s5, short* __restrict__ h5, short* __restrict__ l5, int e5)
{
    int t = blockIdx.x * 256 + threadIdx.x;
    if (t >= e5) return;
    const float* src; short* hi; short* lo; int base;
    if      (t < e0) { src = s0; hi = h0; lo = l0; base = 0;  }
    else if (t < e1) { src = s1; hi = h1; lo = l1; base = e0; }
    else if (t < e2) { src = s2; hi = h2; lo = l2; base = e1; }
    else if (t < e3) { src = s3; hi = h3; lo = l3; base = e2; }
    else if (t < e4) { src = s4; hi = h4; lo = l4; base = e3; }
    else             { src = s5; hi = h5; lo = l5; base = e4; }
    int u = t - base;
    float4 v = ((const float4*)src)[u];
    float x[4] = {v.x, v.y, v.z, v.w};
    short h[4], l[4];
    #pragma unroll
    for (int e = 0; e < 4; ++e) split1(x[e], h[e], l[e]);
    ((short4*)hi)[u] = make_short4(h[0], h[1], h[2], h[3]);
    ((short4*)lo)[u] = make_short4(l[0], l[1], l[2], l[3]);
}

// ---------------------------------------------------------------------------
// GRU dual GEMM via MFMA (R14-proven): grid(144) x 512 thr (8 waves),
// 32-col tiles. bx<72: gi cols = x @ Wih^T; else gh. Waves split K=768
// eight ways (3 k-tiles each), in-register accum, LDS reduce (7 writers),
// wave0 stores f32 to gigh.
// ---------------------------------------------------------------------------
__global__ __launch_bounds__(512) void k_gru_mfma(
    const short* __restrict__ xhi, const short* __restrict__ xlo, long ldx, int pickmode,
    const int* __restrict__ gopd, int i, int jm1,
    const short* __restrict__ pchi, const short* __restrict__ pclo,
    const short* __restrict__ pnhi, const short* __restrict__ pnlo,
    const short* __restrict__ pvhi, const short* __restrict__ pvlo,
    const short* __restrict__ hhi, const short* __restrict__ hlo, long ldh,
    const short* __restrict__ Wih_hi, const short* __restrict__ Wih_lo,
    const short* __restrict__ Whh_hi, const short* __restrict__ Whh_lo,
    float* __restrict__ C)
{
    const int tid  = threadIdx.x;
    const int lane = tid & 63;
    const int w    = tid >> 6;          // 0..7
    const int bx   = blockIdx.x;
    const bool hside = bx >= 72;
    const int n0 = (hside ? bx - 72 : bx) * 32;
    const int koff = (lane >> 4) * 8;

    const short* ahi[4]; const short* alo[4];
    #pragma unroll
    for (int rt = 0; rt < 4; ++rt) {
        int r = rt * 16 + (lane & 15);
        long off;
        const short *bh_, *bl_;
        if (hside) { bh_ = hhi; bl_ = hlo; off = (long)r * ldh; }
        else if (!pickmode) { bh_ = xhi; bl_ = xlo; off = (long)r * ldx; }
        else {
            int idx = gopd[(r * E_ + i) * A_ + jm1];
            if (idx < C_)           { bh_ = pchi; bl_ = pclo; off = (long)idx * H_; }
            else if (idx < C_ + M_) { bh_ = pnhi; bl_ = pnlo; off = ((long)r * M_ + (idx - C_)) * H_; }
            else                    { bh_ = pvhi; bl_ = pvlo; off = ((long)r * E_ + (idx - C_ - M_)) * H_; }
        }
        ahi[rt] = bh_ + off + koff;
        alo[rt] = bl_ + off + koff;
    }
    const short* whi[2]; const short* wlo[2];
    const short* WH = hside ? Whh_hi : Wih_hi;
    const short* WL = hside ? Whh_lo : Wih_lo;
    #pragma unroll
    for (int nt = 0; nt < 2; ++nt) {
        long off = (long)(n0 + nt * 16 + (lane & 15)) * H_ + koff;
        whi[nt] = WH + off;
        wlo[nt] = WL + off;
    }

    f32x4 acc[4][2];
    #pragma unroll
    for (int rt = 0; rt < 4; ++rt)
        #pragma unroll
        for (int nt = 0; nt < 2; ++nt) acc[rt][nt] = (f32x4){0.f, 0.f, 0.f, 0.f};

    for (int kt = w * 3; kt < w * 3 + 3; ++kt) {
        const int kb = kt * 32;
        short8 Ah[4], Al[4];
        #pragma unroll
        for (int rt = 0; rt < 4; ++rt) {
            Ah[rt] = *(const short8*)(ahi[rt] + kb);
            Al[rt] = *(const short8*)(alo[rt] + kb);
        }
        #pragma unroll
        for (int nt = 0; nt < 2; ++nt) {
            short8 Bh = *(const short8*)(whi[nt] + kb);
            short8 Bl = *(const short8*)(wlo[nt] + kb);
            #pragma unroll
            for (int rt = 0; rt < 4; ++rt) {
                acc[rt][nt] = MFMA16(Ah[rt], Bh, acc[rt][nt]);
                acc[rt][nt] = MFMA16(Ah[rt], Bl, acc[rt][nt]);
                acc[rt][nt] = MFMA16(Al[rt], Bh, acc[rt][nt]);
            }
        }
    }

    __shared__ f32x4 Lr[56][64];        // 7 writer-waves x 8 frags
    if (w > 0) {
        #pragma unroll
        for (int rt = 0; rt < 4; ++rt)
            #pragma unroll
            for (int nt = 0; nt < 2; ++nt)
                Lr[(w - 1) * 8 + rt * 2 + nt][lane] = acc[rt][nt];
    }
    __syncthreads();
    if (w == 0) {
        float* Cb = C + (hside ? 2304 : 0) + n0;
        #pragma unroll
        for (int rt = 0; rt < 4; ++rt)
            #pragma unroll
            for (int nt = 0; nt < 2; ++nt) {
                int f = rt * 2 + nt;
                f32x4 s = acc[rt][nt];
                #pragma unroll
                for (int q = 0; q < 7; ++q) s = s + Lr[q * 8 + f][lane];
                int col = nt * 16 + (lane & 15);
                int rb  = rt * 16 + ((lane >> 4) << 2);
                #pragma unroll
                for (int r = 0; r < 4; ++r)
                    Cb[(long)(rb + r) * 4608 + col] = s[r];
            }
    }
}

// ---------------------------------------------------------------------------
// Projection GEMM: A f32 (cvt in-reg, runs once), W pre-split bf16.
// NOW 8 waves (512 thr): waves split 48 k-tiles 8 ways (6 each).
// ---------------------------------------------------------------------------
__global__ __launch_bounds__(512) void k_proj_mfma(
    const float* __restrict__ Ab, long lda, const int* __restrict__ gidx, int Mm,
    const short* __restrict__ Whi, const short* __restrict__ Wlo, int wld,
    float* __restrict__ C, int ldc)
{
    const int tid  = threadIdx.x;
    const int lane = tid & 63;
    const int w    = tid >> 6;          // 0..7
    const int n0 = blockIdx.x * 64;
    const int r0 = blockIdx.y * 64;
    const int koff = (lane >> 4) * 8;

    const float* arow[4];
    #pragma unroll
    for (int rt = 0; rt < 4; ++rt) {
        int r = r0 + rt * 16 + (lane & 15);
        int rr = r < Mm ? r : (Mm - 1);
        const float* s = gidx ? (Ab + (long)gidx[rr] * lda) : (Ab + (long)rr * lda);
        arow[rt] = s + koff;
    }
    const short* whi[4]; const short* wlo[4];
    #pragma unroll
    for (int nt = 0; nt < 4; ++nt) {
        long off = (long)(n0 + nt * 16 + (lane & 15)) * wld + koff;
        whi[nt] = Whi + off; wlo[nt] = Wlo + off;
    }

    f32x4 acc[4][4];
    #pragma unroll
    for (int rt = 0; rt < 4; ++rt)
        #pragma unroll
        for (int nt = 0; nt < 4; ++nt) acc[rt][nt] = (f32x4){0.f, 0.f, 0.f, 0.f};

    for (int kt = w * 6; kt < w * 6 + 6; ++kt) {
        const int kb = kt * 32;
        short8 ah[4], al[4];
        #pragma unroll
        for (int rt = 0; rt < 4; ++rt) {
            float4 p0 = *(const float4*)(arow[rt] + kb);
            float4 p1 = *(const float4*)(arow[rt] + kb + 4);
            cvt8(p0, p1, ah[rt], al[rt]);
        }
        #pragma unroll
        for (int nt = 0; nt < 4; ++nt) {
            short8 Bh = *(const short8*)(whi[nt] + kb);
            short8 Bl = *(const short8*)(wlo[nt] + kb);
            #pragma unroll
            for (int rt = 0; rt < 4; ++rt) {
                acc[rt][nt] = MFMA16(ah[rt], Bh, acc[rt][nt]);
                acc[rt][nt] = MFMA16(ah[rt], Bl, acc[rt][nt]);
                acc[rt][nt] = MFMA16(al[rt], Bh, acc[rt][nt]);
            }
        }
    }

    __shared__ f32x4 Lr[112][64];       // 7 writer-waves x 16 frags
    if (w > 0) {
        #pragma unroll
        for (int rt = 0; rt < 4; ++rt)
            #pragma unroll
            for (int nt = 0; nt < 4; ++nt)
                Lr[(w - 1) * 16 + rt * 4 + nt][lane] = acc[rt][nt];
    }
    __syncthreads();
    if (w == 0) {
        #pragma unroll
        for (int rt = 0; rt < 4; ++rt)
            #pragma unroll
            for (int nt = 0; nt < 4; ++nt) {
                int f = rt * 4 + nt;
                f32x4 s = acc[rt][nt];
                #pragma unroll
                for (int q = 0; q < 7; ++q) s = s + Lr[q * 16 + f][lane];
                int col = n0 + nt * 16 + (lane & 15);
                int rb  = r0 + rt * 16 + ((lane >> 4) << 2);
                #pragma unroll
                for (int r = 0; r < 4; ++r)
                    if (rb + r < Mm) C[(long)(rb + r) * ldc + col] = s[r];
            }
    }
}

// Gates (layer-0): read gi|gh, biases, hnew = (1-z)*n + z*h (+ shadow)
__global__ void k_gates2(const float* __restrict__ GI,
                         const float* __restrict__ h, long ldh,
                         const float* __restrict__ bih, const float* __restrict__ bhh,
                         float* __restrict__ hnew,
                         short* __restrict__ hnhi, short* __restrict__ hnlo)
{
    int t = blockIdx.x * 256 + threadIdx.x;       // 64*768
    int b = t / 768, c = t - b * 768;
    const float* gb = GI + (long)b * 4608;
    float ir  = gb[c]        + bih[c];
    float iz  = gb[768 + c]  + bih[768 + c];
    float in_ = gb[1536 + c] + bih[1536 + c];
    float hr  = gb[2304 + c] + bhh[c];
    float hz  = gb[3072 + c] + bhh[768 + c];
    float hn  = gb[3840 + c] + bhh[1536 + c];
    float r  = 1.f / (1.f + expf(-(ir + hr)));
    float z_ = 1.f / (1.f + expf(-(iz + hz)));
    float n  = tanhf(in_ + r * hn);
    float hp = h[(long)b * ldh + c];
    float v = (1.f - z_) * n + z_ * hp;
    hnew[t] = v;
    short sh, sl; split1(v, sh, sl);
    hnhi[t] = sh; hnlo[t] = sl;
}

// Add bias then LayerNorm each 768-wide row of X in place (+ shadow).
__global__ void k_ln2(float* __restrict__ X, const float* __restrict__ bias,
                      const float* __restrict__ g, const float* __restrict__ be,
                      short* __restrict__ Xhi, short* __restrict__ Xlo)
{
    int row = blockIdx.x, tid = threadIdx.x;
    __shared__ float red[256];
    float* xr = X + (long)row * 768;
    float v[3];
    #pragma unroll
    for (int it = 0; it < 3; ++it) {
        int c2 = tid + it * 256;
        v[it] = xr[c2] + bias[c2];
    }
    float s = v[0] + v[1] + v[2];
    red[tid] = s; __syncthreads();
    for (int o = 128; o > 0; o >>= 1) { if (tid < o) red[tid] += red[tid + o]; __syncthreads(); }
    float mu = red[0] / 768.f;
    __syncthreads();
    float vv = 0.f;
    #pragma unroll
    for (int it = 0; it < 3; ++it) { float d = v[it] - mu; vv += d * d; }
    red[tid] = vv; __syncthreads();
    for (int o = 128; o > 0; o >>= 1) { if (tid < o) red[tid] += red[tid + o]; __syncthreads(); }
    float inv = 1.f / sqrtf(red[0] / 768.f + 1e-5f);
    #pragma unroll
    for (int it = 0; it < 3; ++it) {
        int c2 = tid + it * 256;
        float o2 = (v[it] - mu) * inv * g[c2] + be[c2];
        xr[c2] = o2;
        short sh, sl; split1(o2, sh, sl);
        Xhi[(long)row * 768 + c2] = sh;
        Xlo[(long)row * 768 + c2] = sl;
    }
}

// ---------------------------------------------------------------------------
// Fused op head with optional cg-gates-L1 prologue (do_gates).
// ---------------------------------------------------------------------------
__global__ __launch_bounds__(256) void k_ophead_fused(
    int do_gates,
    const float* __restrict__ GI,
    const float* __restrict__ bihg, const float* __restrict__ bhhg,
    const float* __restrict__ hp, long ldhp,
    float* __restrict__ cvf, short* __restrict__ cvhi, short* __restrict__ cvlo,
    const float* __restrict__ W1, const float* __restrict__ b1,
    const float* __restrict__ W2, const float* __restrict__ b2,
    float* __restrict__ op_out, int i)
{
    int b = blockIdx.x, tid = threadIdx.x;
    __shared__ float xs[768];
    __shared__ float hs[384];

    if (do_gates) {
        const float* gb = GI + (long)b * 4608;
        #pragma unroll
        for (int it = 0; it < 3; ++it) {
            int c2 = tid + it * 256;
            float ir  = gb[c2]        + bihg[c2];
            float iz  = gb[768 + c2]  + bihg[768 + c2];
            float in_ = gb[1536 + c2] + bihg[1536 + c2];
            float hr  = gb[2304 + c2] + bhhg[c2];
            float hz  = gb[3072 + c2] + bhhg[768 + c2];
            float hn  = gb[3840 + c2] + bhhg[1536 + c2];
            float r  = 1.f / (1.f + expf(-(ir + hr)));
            float z_ = 1.f / (1.f + expf(-(iz + hz)));
            float n  = tanhf(in_ + r * hn);
            float hpv = hp[(long)b * ldhp + c2];
            float v = (1.f - z_) * n + z_ * hpv;
            xs[c2] = v;
            cvf[(long)b * 768 + c2] = v;
            short sh, sl; split1(v, sh, sl);
            cvhi[(long)b * 768 + c2] = sh;
            cvlo[(long)b * 768 + c2] = sl;
        }
    } else {
        const float* xr = cvf + (long)b * 768;
        #pragma unroll
        for (int it = 0; it < 3; ++it) xs[tid + it * 256] = xr[tid + it * 256];
    }
    __syncthreads();

    for (int c = tid; c < 384; c += 256) {
        const float* wr = W1 + (long)c * 768;
        float acc = 0.f;
        #pragma unroll 8
        for (int k = 0; k < 768; k += 4) {
            float4 xv = *(const float4*)&xs[k];
            float4 wv = *(const float4*)(wr + k);
            acc += xv.x * wv.x + xv.y * wv.y + xv.z * wv.z + xv.w * wv.w;
        }
        hs[c] = fmaxf(acc + b1[c], 0.f);
    }
    __syncthreads();

    int c = tid >> 3, g = tid & 7;
    float acc = 0.f;
    if (c < OP_) {
        const float* wr = W2 + (long)c * HH_;
        #pragma unroll
        for (int t = 0; t < 12; ++t) {
            int k = (g + 8 * t) * 4;
            float4 xv = *(const float4*)&hs[k];
            float4 wv = *(const float4*)(wr + k);
            acc += xv.x * wv.x + xv.y * wv.y + xv.z * wv.z + xv.w * wv.w;
        }
    }
    acc += __shfl_xor(acc, 1);
    acc += __shfl_xor(acc, 2);
    acc += __shfl_xor(acc, 4);
    if (c < OP_ && g == 0)
        op_out[((long)b * E_ + i) * OP_ + c] = acc + b2[c];
}

// ---------------------------------------------------------------------------
// Fused od head with og-gates-L1 prologue.
// ---------------------------------------------------------------------------
__global__ __launch_bounds__(256) void k_odhead(
    const float* __restrict__ GI,
    const float* __restrict__ bihg, const float* __restrict__ bhhg,
    const float* __restrict__ hp, long ldhp,
    float* __restrict__ hx1f, short* __restrict__ hx1hi, short* __restrict__ hx1lo,
    const float* __restrict__ W1, const float* __restrict__ b1,
    const float* __restrict__ W2, const float* __restrict__ b2,
    float* __restrict__ od_base, long ldl,
    float* __restrict__ prev, int i,
    const float* __restrict__ pcb, const float* __restrict__ pnb,
    short* __restrict__ pvhi, short* __restrict__ pvlo,
    int do_final)
{
    int b = blockIdx.x, tid = threadIdx.x;
    __shared__ float xs[768];
    __shared__ float ps[768];
    __shared__ float hidL[24];
    __shared__ float lg[48];
    __shared__ float red[256];
    __shared__ int s_oidx;

    {
        const float* gb = GI + (long)b * 4608;
        #pragma unroll
        for (int it = 0; it < 3; ++it) {
            int c2 = tid + it * 256;
            float ir  = gb[c2]        + bihg[c2];
            float iz  = gb[768 + c2]  + bihg[768 + c2];
            float in_ = gb[1536 + c2] + bihg[1536 + c2];
            float hr  = gb[2304 + c2] + bhhg[c2];
            float hz  = gb[3072 + c2] + bhhg[768 + c2];
            float hn  = gb[3840 + c2] + bhhg[1536 + c2];
            float r  = 1.f / (1.f + expf(-(ir + hr)));
            float z_ = 1.f / (1.f + expf(-(iz + hz)));
            float n  = tanhf(in_ + r * hn);
            float hpv = hp[(long)b * ldhp + c2];
            float v = (1.f - z_) * n + z_ * hpv;
            xs[c2] = v;
            hx1f[(long)b * 768 + c2] = v;
            short sh, sl; split1(v, sh, sl);
            hx1hi[(long)b * 768 + c2] = sh;
            hx1lo[(long)b * 768 + c2] = sl;
        }
    }
    __syncthreads();

    int c = tid >> 3, g = tid & 7;
    float acc = 0.f;
    if (c < 24) {
        const float* wr = W1 + (long)c * 768;
        #pragma unroll
        for (int t = 0; t < 24; ++t) {
            int k = (g + 8 * t) * 4;
            float4 xv = *(const float4*)&xs[k];
            float4 wv = *(const float4*)(wr + k);
            acc += xv.x * wv.x + xv.y * wv.y + xv.z * wv.z + xv.w * wv.w;
        }
    }
    acc += __shfl_xor(acc, 1);
    acc += __shfl_xor(acc, 2);
    acc += __shfl_xor(acc, 4);
    if (c < 24 && g == 0) hidL[c] = fmaxf(acc + b1[c], 0.f);
    __syncthreads();

    if (tid < 48) {
        float a2 = b2[tid];
        const float* w2 = W2 + tid * 24;
        #pragma unroll
        for (int k = 0; k < 24; ++k) a2 += hidL[k] * w2[k];
        lg[tid] = a2;
        od_base[(long)b * ldl + tid] = a2;
    }

    long poff = ((long)b * E_ + i) * 768;
    float* prow = prev + poff;
    float m = -3.4e38f;
    #pragma unroll
    for (int it = 0; it < 3; ++it) m = fmaxf(m, prow[tid + it * 256]);
    red[tid] = m; __syncthreads();
    for (int o = 128; o > 0; o >>= 1) { if (tid < o) red[tid] = fmaxf(red[tid], red[tid + o]); __syncthreads(); }
    float m0 = red[0];

    if (tid == 0) {      // first-max tie semantics (matches jnp.argmax)
        float best = lg[0]; int bi = 0;
        for (int k2 = 1; k2 < K_; ++k2) { float v = lg[k2]; if (v > best) { best = v; bi = k2; } }
        s_oidx = bi;
    }
    __syncthreads();
    int oidx = s_oidx;
    bool empty0 = (m0 == 0.0f);
    bool cond = (oidx == 0) && empty0;
    if (cond) {
        #pragma unroll
        for (int it = 0; it < 3; ++it) {
            int c2 = tid + it * 256;
            float v = xs[c2];
            prow[c2] = v;
            short sh, sl; split1(v, sh, sl);
            pvhi[poff + c2] = sh; pvlo[poff + c2] = sl;
        }
    }
    __syncthreads();

    if (!do_final) return;

    float mfin;
    if (cond) {
        float mx = -3.4e38f;
        #pragma unroll
        for (int it = 0; it < 3; ++it) mx = fmaxf(mx, xs[tid + it * 256]);
        red[tid] = mx; __syncthreads();
        for (int o = 128; o > 0; o >>= 1) { if (tid < o) red[tid] = fmaxf(red[tid], red[tid + o]); __syncthreads(); }
        mfin = red[0];
    } else {
        mfin = m0;
    }

    const float* src;
    if (oidx < C_)            src = pcb + (long)oidx * 768;
    else if (oidx < C_ + M_)  src = pnb + ((long)b * M_ + (oidx - C_)) * 768;
    else                      src = prev + ((long)b * E_ + (oidx - C_ - M_)) * 768;
    #pragma unroll
    for (int it = 0; it < 3; ++it) ps[tid + it * 256] = src[tid + it * 256];
    __syncthreads();

    if (mfin == 0.0f) {
        #pragma unroll
        for (int it = 0; it < 3; ++it) {
            int c2 = tid + it * 256;
            float v = ps[c2];
            prow[c2] = v;
            short sh, sl; split1(v, sh, sl);
            pvhi[poff + c2] = sh; pvlo[poff + c2] = sl;
        }
    }
}

// Build num_vec: for (b,m) find first/last position with number_mask==m+1
__global__ void k_numvec(const float* __restrict__ inp, const int* __restrict__ nmask,
                         float* __restrict__ numvec)
{
    int b = blockIdx.x / M_, m = blockIdx.x % M_;
    int tid = threadIdx.x;
    int fmin = S_, lmax = -1;
    for (int s = tid; s < S_; s += 256) {
        if (nmask[b * S_ + s] == m + 1) {
            if (s < fmin) fmin = s;
            if (s > lmax) lmax = s;
        }
    }
    __shared__ int sf[256], sl[256];
    sf[tid] = fmin; sl[tid] = lmax; __syncthreads();
    for (int o = 128; o > 0; o >>= 1) {
        if (tid < o) {
            sf[tid] = min(sf[tid], sf[tid + o]);
            sl[tid] = max(sl[tid], sl[tid + o]);
        }
        __syncthreads();
    }
    int first = sf[0], last = sl[0];
    bool exists = (last >= 0);
    if (!exists) { first = 0; last = 0; }
    const float* fv = inp + ((long)b * S_ + first) * H_;
    const float* lv = inp + ((long)b * S_ + last) * H_;
    float* dst = numvec + ((long)b * M_ + m) * H2_;
    for (int h = tid; h < H_; h += 256) {
        dst[h]      = exists ? fv[h] : 0.f;
        dst[H_ + h] = exists ? lv[h] : 0.f;
    }
}

__global__ void k_copy_cv(const float* __restrict__ inp, float* __restrict__ cvv,
                          short* __restrict__ cvhi, short* __restrict__ cvlo)
{
    int b = blockIdx.x;
    for (int h = threadIdx.x; h < H_; h += 256) {
        float v = inp[(long)b * S_ * H_ + h];
        cvv[b * H_ + h] = v;
        short sh, sl; split1(v, sh, sl);
        cvhi[b * H_ + h] = sh; cvlo[b * H_ + h] = sl;
    }
}

// ---------------------------------------------------------------------------
extern "C" void kernel_launch(void* const* d_in, const int* in_sizes, int n_in,
                              void* d_out, int out_size, void* d_ws, size_t ws_size,
                              hipStream_t stream)
{
    const float* inp    = (const float*)d_in[0];
    const int*   nmask  = (const int*)  d_in[3];
    const int*   gops   = (const int*)  d_in[4];
    const int*   gopd   = (const int*)  d_in[5];
    const float* constv = (const float*)d_in[6];
    const float* opv    = (const float*)d_in[7];
    const float* opj_W  = (const float*)d_in[8];
    const float* opj_b  = (const float*)d_in[9];
    const float* opj_g  = (const float*)d_in[10];
    const float* opj_be = (const float*)d_in[11];
    const float* odj_W  = (const float*)d_in[12];
    const float* odj_b  = (const float*)d_in[13];
    const float* odj_g  = (const float*)d_in[14];
    const float* odj_be = (const float*)d_in[15];
    const float* opc_W1 = (const float*)d_in[16];
    const float* opc_b1 = (const float*)d_in[17];
    const float* opc_W2 = (const float*)d_in[18];
    const float* opc_b2 = (const float*)d_in[19];
    const float* odc_W1 = (const float*)d_in[20];
    const float* odc_b1 = (const float*)d_in[21];
    const float* odc_W2 = (const float*)d_in[22];
    const float* odc_b2 = (const float*)d_in[23];
    const float* og_Wih = (const float*)d_in[24];
    const float* og_Whh = (const float*)d_in[25];
    const float* og_bih = (const float*)d_in[26];
    const float* og_bhh = (const float*)d_in[27];
    const float* cg_Wih = (const float*)d_in[28];
    const float* cg_Whh = (const float*)d_in[29];
    const float* cg_bih = (const float*)d_in[30];
    const float* cg_bhh = (const float*)d_in[31];

    float* op_out = (float*)d_out;                  // (B, E, OP)
    float* od_out = op_out + (long)B_ * E_ * OP_;   // (B, E, A, K)

    // ---- workspace partition ----
    float* ws      = (float*)d_ws;
    float* num_vec = ws; ws += (long)B_ * M_ * H2_;       // 1024x1536
    float* pn      = ws; ws += (long)B_ * M_ * H_;        // 1024x768
    float* pcb     = ws; ws += (long)64 * H_;             // 24 used (pad 64)
    float* gopv    = ws; ws += (long)B_ * E_ * H_;        // 512x768
    float* prev    = ws; ws += (long)B_ * E_ * H_;
    float* gigh    = ws; ws += (long)B_ * 4608;           // gi | gh
    float* cv      = ws; ws += (long)B_ * H_;
    float* h0      = ws; ws += (long)B_ * H_;
    float* hx0     = ws; ws += (long)B_ * H_;
    float* hx1     = ws; ws += (long)B_ * H_;

    // bf16 hi/lo shadows (shorts; all sizes even)
    auto alloc_s = [&](long elems) -> short* {
        short* p = (short*)ws; ws += elems / 2; return p;
    };
    const long nOG = (long)2 * G3_ * H_;   // per GRU stack (2 layers)
    short* og_ih_hi = alloc_s(nOG); short* og_ih_lo = alloc_s(nOG);
    short* og_hh_hi = alloc_s(nOG); short* og_hh_lo = alloc_s(nOG);
    short* cg_ih_hi = alloc_s(nOG); short* cg_ih_lo = alloc_s(nOG);
    short* cg_hh_hi = alloc_s(nOG); short* cg_hh_lo = alloc_s(nOG);
    const long nPJ = (long)H_ * H2_;
    short* odj_hi = alloc_s(nPJ); short* odj_lo = alloc_s(nPJ);
    short* opj_hi = alloc_s(nPJ); short* opj_lo = alloc_s(nPJ);
    short* pn_hi  = alloc_s((long)B_ * M_ * H_); short* pn_lo  = alloc_s((long)B_ * M_ * H_);
    short* pc_hi  = alloc_s((long)64 * H_);      short* pc_lo  = alloc_s((long)64 * H_);
    short* gv_hi  = alloc_s((long)B_ * E_ * H_); short* gv_lo  = alloc_s((long)B_ * E_ * H_);
    short* pv_hi  = alloc_s((long)B_ * E_ * H_); short* pv_lo  = alloc_s((long)B_ * E_ * H_);
    short* cv_hi  = alloc_s((long)B_ * H_);      short* cv_lo  = alloc_s((long)B_ * H_);
    short* h0_hi  = alloc_s((long)B_ * H_);      short* h0_lo  = alloc_s((long)B_ * H_);
    short* hx0_hi = alloc_s((long)B_ * H_);      short* hx0_lo = alloc_s((long)B_ * H_);
    short* hx1_hi = alloc_s((long)B_ * H_);      short* hx1_lo = alloc_s((long)B_ * H_);

    hipMemsetAsync(prev, 0, (size_t)B_ * E_ * H_ * sizeof(float), stream);
    hipMemsetAsync(pv_hi, 0, (size_t)2 * B_ * E_ * H_ * sizeof(short), stream);

    // ---- weight pre-split (single dispatch over 6 regions) ----
    {
        int nOG4 = (int)(nOG / 4), nPJ4 = (int)(nPJ / 4);
        int e0 = nOG4, e1 = 2 * nOG4, e2 = 3 * nOG4, e3 = 4 * nOG4;
        int e4 = e3 + nPJ4, e5 = e4 + nPJ4;
        k_split_all<<<(e5 + 255) / 256, 256, 0, stream>>>(
            og_Wih, og_ih_hi, og_ih_lo, e0,
            og_Whh, og_hh_hi, og_hh_lo, e1,
            cg_Wih, cg_ih_hi, cg_ih_lo, e2,
            cg_Whh, cg_hh_hi, cg_hh_lo, e3,
            odj_W,  odj_hi,  odj_lo,  e4,
            opj_W,  opj_hi,  opj_lo,  e5);
    }

    // ---- preprocessing ----
    k_numvec<<<B_ * M_, 256, 0, stream>>>(inp, nmask, num_vec);

    k_proj_mfma<<<dim3(12, 16), 512, 0, stream>>>(num_vec, H2_, nullptr, 1024,
                                                  odj_hi, odj_lo, H2_, pn, H_);
    k_ln2<<<1024, 256, 0, stream>>>(pn, odj_b, odj_g, odj_be, pn_hi, pn_lo);

    k_proj_mfma<<<dim3(12, 1), 512, 0, stream>>>(constv, H2_, nullptr, C_,
                                                 odj_hi, odj_lo, H2_, pcb, H_);
    k_ln2<<<C_, 256, 0, stream>>>(pcb, odj_b, odj_g, odj_be, pc_hi, pc_lo);

    k_proj_mfma<<<dim3(12, 8), 512, 0, stream>>>(opv, H2_, gops, 512,
                                                 opj_hi, opj_lo, H2_, gopv, H_);
    k_ln2<<<512, 256, 0, stream>>>(gopv, opj_b, opj_g, opj_be, gv_hi, gv_lo);

    k_copy_cv<<<B_, 256, 0, stream>>>(inp, cv, cv_hi, cv_lo);

    // ---- decode loop ----
    const long ldE = (long)E_ * H_;
    const long lW  = (long)G3_ * H_;   // layer-1 weight offset

    for (int i = 0; i < E_; ++i) {
        if (i > 0) {
            const float* hrow = prev + (long)(i - 1) * H_;
            const short* hrhi = pv_hi + (long)(i - 1) * H_;
            const short* hrlo = pv_lo + (long)(i - 1) * H_;
            k_gru_mfma<<<144, 512, 0, stream>>>(cv_hi, cv_lo, H_, 0, nullptr, 0, 0,
                                                nullptr, nullptr, nullptr, nullptr, nullptr, nullptr,
                                                hrhi, hrlo, ldE,
                                                cg_ih_hi, cg_ih_lo, cg_hh_hi, cg_hh_lo, gigh);
            k_gates2<<<192, 256, 0, stream>>>(gigh, hrow, ldE, cg_bih, cg_bhh, h0, h0_hi, h0_lo);
            k_gru_mfma<<<144, 512, 0, stream>>>(h0_hi, h0_lo, H_, 0, nullptr, 0, 0,
                                                nullptr, nullptr, nullptr, nullptr, nullptr, nullptr,
                                                hrhi, hrlo, ldE,
                                                cg_ih_hi + lW, cg_ih_lo + lW,
                                                cg_hh_hi + lW, cg_hh_lo + lW, gigh);
            k_ophead_fused<<<B_, 256, 0, stream>>>(1, gigh, cg_bih + G3_, cg_bhh + G3_,
                                                   hrow, ldE, cv, cv_hi, cv_lo,
                                                   opc_W1, opc_b1, opc_W2, opc_b2, op_out, i);
        } else {
            k_ophead_fused<<<B_, 256, 0, stream>>>(0, gigh, cg_bih, cg_bhh,
                                                   cv, H_, cv, cv_hi, cv_lo,
                                                   opc_W1, opc_b1, opc_W2, opc_b2, op_out, i);
        }

        for (int j = 0; j < A_; ++j) {
            const short *xhi, *xlo; long ldx; int pickm;
            if (j == 0) { xhi = gv_hi + (long)i * H_; xlo = gv_lo + (long)i * H_; ldx = ldE; pickm = 0; }
            else        { xhi = nullptr; xlo = nullptr; ldx = 0; pickm = 1; }
            const float* hp0 = (j == 0) ? cv : hx0;
            const float* hp1 = (j == 0) ? cv : hx1;
            const short* hp0hi = (j == 0) ? cv_hi : hx0_hi;
            const short* hp0lo = (j == 0) ? cv_lo : hx0_lo;
            const short* hp1hi = (j == 0) ? cv_hi : hx1_hi;
            const short* hp1lo = (j == 0) ? cv_lo : hx1_lo;

            k_gru_mfma<<<144, 512, 0, stream>>>(xhi, xlo, ldx, pickm, gopd, i, j - 1,
                                                pc_hi, pc_lo, pn_hi, pn_lo, pv_hi, pv_lo,
                                                hp0hi, hp0lo, H_,
                                                og_ih_hi, og_ih_lo, og_hh_hi, og_hh_lo, gigh);
            k_gates2<<<192, 256, 0, stream>>>(gigh, hp0, H_, og_bih, og_bhh, hx0, hx0_hi, hx0_lo);
            k_gru_mfma<<<144, 512, 0, stream>>>(hx0_hi, hx0_lo, H_, 0, nullptr, 0, 0,
                                                nullptr, nullptr, nullptr, nullptr, nullptr, nullptr,
                                                hp1hi, hp1lo, H_,
                                                og_ih_hi + lW, og_ih_lo + lW,
                                                og_hh_hi + lW, og_hh_lo + lW, gigh);

            float* od_base = od_out + ((long)i * A_ + j) * K_;
            k_odhead<<<B_, 256, 0, stream>>>(gigh, og_bih + G3_, og_bhh + G3_,
                                             hp1, H_, hx1, hx1_hi, hx1_lo,
                                             odc_W1, odc_b1, odc_W2, odc_b2,
                                             od_base, (long)E_ * A_ * K_,
                                             prev, i, pcb, pn, pv_hi, pv_lo,
                                             (j == A_ - 1) ? 1 : 0);
        }
    }
}

// Round 16
// 1394.785 us; speedup vs baseline: 1.2009x; 1.0062x over previous
//
#include <hip/hip_runtime.h>
#include <math.h>

// Problem constants
constexpr int B_  = 64;
constexpr int S_  = 512;
constexpr int H_  = 768;
constexpr int H2_ = 1536;   // 2H
constexpr int G3_ = 2304;   // 3H
constexpr int OP_ = 18;
constexpr int C_  = 24;
constexpr int M_  = 16;
constexpr int E_  = 8;
constexpr int A_  = 3;
constexpr int K_  = 48;     // C+M+E
constexpr int HH_ = 384;    // H/2

using f32x4  = __attribute__((ext_vector_type(4))) float;
using short8 = __attribute__((ext_vector_type(8))) short;

#define MFMA16(a, b, c) __builtin_amdgcn_mfma_f32_16x16x32_bf16((a), (b), (c), 0, 0, 0)

// Split f32 into bf16 hi (truncate) + bf16 lo (residual, truncate).
__device__ __forceinline__ void split1(float x, short& h, short& l)
{
    union { float f; unsigned u; } a; a.f = x;
    h = (short)(a.u >> 16);
    union { unsigned u; float f; } hb; hb.u = a.u & 0xffff0000u;
    union { float f; unsigned u; } r; r.f = x - hb.f;
    l = (short)(r.u >> 16);
}

__device__ __forceinline__ void cvt8(float4 p0, float4 p1, short8& hi, short8& lo)
{
    float x[8] = {p0.x, p0.y, p0.z, p0.w, p1.x, p1.y, p1.z, p1.w};
    #pragma unroll
    for (int e = 0; e < 8; ++e) { short h, l; split1(x[e], h, l); hi[e] = h; lo[e] = l; }
}

// Single-dispatch bulk splitter over 6 weight regions (float4 units).
__global__ void k_split_all(
    const float* __restrict__ s0, short* __restrict__ h0, short* __restrict__ l0, int e0,
    const float* __restrict__ s1, short* __restrict__ h1, short* __restrict__ l1, int e1,
    const float* __restrict__ s2, short* __restrict__ h2, short* __restrict__ l2, int e2,
    const float* __restrict__ s3, short* __restrict__ h3, short* __restrict__ l3, int e3,
    const float* __restrict__ s4, short* __restrict__ h4, short* __restrict__ l4, int e4,
    const float* __restrict__ s5, short* __restrict__ h5, short* __restrict__ l5, int e5)
{
    int t = blockIdx.x * 256 + threadIdx.x;
    if (t >= e5) return;
    const float* src; short* hi; short* lo; int base;
    if      (t < e0) { src = s0; hi = h0; lo = l0; base = 0;  }
    else if (t < e1) { src = s1; hi = h1; lo = l1; base = e0; }
    else if (t < e2) { src = s2; hi = h2; lo = l2; base = e1; }
    else if (t < e3) { src = s3; hi = h3; lo = l3; base = e2; }
    else if (t < e4) { src = s4; hi = h4; lo = l4; base = e3; }
    else             { src = s5; hi = h5; lo = l5; base = e4; }
    int u = t - base;
    float4 v = ((const float4*)src)[u];
    float x[4] = {v.x, v.y, v.z, v.w};
    short h[4], l[4];
    #pragma unroll
    for (int e = 0; e < 4; ++e) split1(x[e], h[e], l[e]);
    ((short4*)hi)[u] = make_short4(h[0], h[1], h[2], h[3]);
    ((short4*)lo)[u] = make_short4(l[0], l[1], l[2], l[3]);
}

// ---------------------------------------------------------------------------
// GRU dual GEMM via MFMA: grid(144 or 72 if ghonly) x 512 thr (8 waves),
// 32-col tiles. Waves split K=768 eight ways (3 k-tiles each),
// in-register accum, all-wave LDS exchange, PER-WAVE fragment epilogue
// (wave w sums frag w over w0..w7 order -> bit-identical to R14/R15),
// stores f32 to gigh (ldc 4608).
// ---------------------------------------------------------------------------
__global__ __launch_bounds__(512) void k_gru_mfma(
    int ghonly,
    const short* __restrict__ xhi, const short* __restrict__ xlo, long ldx, int pickmode,
    const int* __restrict__ gopd, int i, int jm1,
    const short* __restrict__ pchi, const short* __restrict__ pclo,
    const short* __restrict__ pnhi, const short* __restrict__ pnlo,
    const short* __restrict__ pvhi, const short* __restrict__ pvlo,
    const short* __restrict__ hhi, const short* __restrict__ hlo, long ldh,
    const short* __restrict__ Wih_hi, const short* __restrict__ Wih_lo,
    const short* __restrict__ Whh_hi, const short* __restrict__ Whh_lo,
    float* __restrict__ C)
{
    const int tid  = threadIdx.x;
    const int lane = tid & 63;
    const int w    = tid >> 6;          // 0..7
    const int bx   = blockIdx.x;
    const bool hside = ghonly || (bx >= 72);
    const int n0 = ((hside && !ghonly) ? bx - 72 : bx) * 32;
    const int koff = (lane >> 4) * 8;

    const short* ahi[4]; const short* alo[4];
    #pragma unroll
    for (int rt = 0; rt < 4; ++rt) {
        int r = rt * 16 + (lane & 15);
        long off;
        const short *bh_, *bl_;
        if (hside) { bh_ = hhi; bl_ = hlo; off = (long)r * ldh; }
        else if (!pickmode) { bh_ = xhi; bl_ = xlo; off = (long)r * ldx; }
        else {
            int idx = gopd[(r * E_ + i) * A_ + jm1];
            if (idx < C_)           { bh_ = pchi; bl_ = pclo; off = (long)idx * H_; }
            else if (idx < C_ + M_) { bh_ = pnhi; bl_ = pnlo; off = ((long)r * M_ + (idx - C_)) * H_; }
            else                    { bh_ = pvhi; bl_ = pvlo; off = ((long)r * E_ + (idx - C_ - M_)) * H_; }
        }
        ahi[rt] = bh_ + off + koff;
        alo[rt] = bl_ + off + koff;
    }
    const short* whi[2]; const short* wlo[2];
    const short* WH = hside ? Whh_hi : Wih_hi;
    const short* WL = hside ? Whh_lo : Wih_lo;
    #pragma unroll
    for (int nt = 0; nt < 2; ++nt) {
        long off = (long)(n0 + nt * 16 + (lane & 15)) * H_ + koff;
        whi[nt] = WH + off;
        wlo[nt] = WL + off;
    }

    f32x4 acc[4][2];
    #pragma unroll
    for (int rt = 0; rt < 4; ++rt)
        #pragma unroll
        for (int nt = 0; nt < 2; ++nt) acc[rt][nt] = (f32x4){0.f, 0.f, 0.f, 0.f};

    for (int kt = w * 3; kt < w * 3 + 3; ++kt) {
        const int kb = kt * 32;
        short8 Ah[4], Al[4];
        #pragma unroll
        for (int rt = 0; rt < 4; ++rt) {
            Ah[rt] = *(const short8*)(ahi[rt] + kb);
            Al[rt] = *(const short8*)(alo[rt] + kb);
        }
        #pragma unroll
        for (int nt = 0; nt < 2; ++nt) {
            short8 Bh = *(const short8*)(whi[nt] + kb);
            short8 Bl = *(const short8*)(wlo[nt] + kb);
            #pragma unroll
            for (int rt = 0; rt < 4; ++rt) {
                acc[rt][nt] = MFMA16(Ah[rt], Bh, acc[rt][nt]);
                acc[rt][nt] = MFMA16(Ah[rt], Bl, acc[rt][nt]);
                acc[rt][nt] = MFMA16(Al[rt], Bh, acc[rt][nt]);
            }
        }
    }

    // all-wave exchange, per-wave fragment reduce+store (order w0..w7)
    __shared__ f32x4 Lr[8][8][64];      // 64 KB
    #pragma unroll
    for (int rt = 0; rt < 4; ++rt)
        #pragma unroll
        for (int nt = 0; nt < 2; ++nt)
            Lr[w][rt * 2 + nt][lane] = acc[rt][nt];
    __syncthreads();
    {
        const int f  = w;               // wave w owns fragment w
        const int rt = f >> 1, nt = f & 1;
        f32x4 s = Lr[0][f][lane];
        #pragma unroll
        for (int q = 1; q < 8; ++q) s = s + Lr[q][f][lane];
        float* Cb = C + (hside ? 2304 : 0) + n0;
        int col = nt * 16 + (lane & 15);
        int rb  = rt * 16 + ((lane >> 4) << 2);
        #pragma unroll
        for (int r = 0; r < 4; ++r)
            Cb[(long)(rb + r) * 4608 + col] = s[r];
    }
}

// ---------------------------------------------------------------------------
// Precompute gi for all (b,i) at once: gi_pre[512][2304] = gopv @ og_Wih0^T.
// grid(72, 8) x 512 thr. Same K-split/order as k_gru_mfma -> bit-identical.
// ---------------------------------------------------------------------------
__global__ __launch_bounds__(512) void k_gi_pre(
    const short* __restrict__ xhi, const short* __restrict__ xlo,   // 512x768
    const short* __restrict__ Whi, const short* __restrict__ Wlo,   // og Wih L0
    float* __restrict__ C)                                          // 512x2304
{
    const int tid  = threadIdx.x;
    const int lane = tid & 63;
    const int w    = tid >> 6;
    const int n0 = blockIdx.x * 32;
    const int r0 = blockIdx.y * 64;
    const int koff = (lane >> 4) * 8;

    const short* ahi[4]; const short* alo[4];
    #pragma unroll
    for (int rt = 0; rt < 4; ++rt) {
        long off = (long)(r0 + rt * 16 + (lane & 15)) * H_ + koff;
        ahi[rt] = xhi + off;
        alo[rt] = xlo + off;
    }
    const short* whi[2]; const short* wlo[2];
    #pragma unroll
    for (int nt = 0; nt < 2; ++nt) {
        long off = (long)(n0 + nt * 16 + (lane & 15)) * H_ + koff;
        whi[nt] = Whi + off;
        wlo[nt] = Wlo + off;
    }

    f32x4 acc[4][2];
    #pragma unroll
    for (int rt = 0; rt < 4; ++rt)
        #pragma unroll
        for (int nt = 0; nt < 2; ++nt) acc[rt][nt] = (f32x4){0.f, 0.f, 0.f, 0.f};

    for (int kt = w * 3; kt < w * 3 + 3; ++kt) {
        const int kb = kt * 32;
        short8 Ah[4], Al[4];
        #pragma unroll
        for (int rt = 0; rt < 4; ++rt) {
            Ah[rt] = *(const short8*)(ahi[rt] + kb);
            Al[rt] = *(const short8*)(alo[rt] + kb);
        }
        #pragma unroll
        for (int nt = 0; nt < 2; ++nt) {
            short8 Bh = *(const short8*)(whi[nt] + kb);
            short8 Bl = *(const short8*)(wlo[nt] + kb);
            #pragma unroll
            for (int rt = 0; rt < 4; ++rt) {
                acc[rt][nt] = MFMA16(Ah[rt], Bh, acc[rt][nt]);
                acc[rt][nt] = MFMA16(Ah[rt], Bl, acc[rt][nt]);
                acc[rt][nt] = MFMA16(Al[rt], Bh, acc[rt][nt]);
            }
        }
    }

    __shared__ f32x4 Lr[8][8][64];
    #pragma unroll
    for (int rt = 0; rt < 4; ++rt)
        #pragma unroll
        for (int nt = 0; nt < 2; ++nt)
            Lr[w][rt * 2 + nt][lane] = acc[rt][nt];
    __syncthreads();
    {
        const int f  = w;
        const int rt = f >> 1, nt = f & 1;
        f32x4 s = Lr[0][f][lane];
        #pragma unroll
        for (int q = 1; q < 8; ++q) s = s + Lr[q][f][lane];
        int col = n0 + nt * 16 + (lane & 15);
        int rb  = r0 + rt * 16 + ((lane >> 4) << 2);
        #pragma unroll
        for (int r = 0; r < 4; ++r)
            C[(long)(rb + r) * G3_ + col] = s[r];
    }
}

// ---------------------------------------------------------------------------
// Projection GEMM: A f32 (cvt in-reg, runs once), W pre-split bf16.
// 8 waves (512 thr): waves split 48 k-tiles 8 ways (6 each).
// ---------------------------------------------------------------------------
__global__ __launch_bounds__(512) void k_proj_mfma(
    const float* __restrict__ Ab, long lda, const int* __restrict__ gidx, int Mm,
    const short* __restrict__ Whi, const short* __restrict__ Wlo, int wld,
    float* __restrict__ C, int ldc)
{
    const int tid  = threadIdx.x;
    const int lane = tid & 63;
    const int w    = tid >> 6;          // 0..7
    const int n0 = blockIdx.x * 64;
    const int r0 = blockIdx.y * 64;
    const int koff = (lane >> 4) * 8;

    const float* arow[4];
    #pragma unroll
    for (int rt = 0; rt < 4; ++rt) {
        int r = r0 + rt * 16 + (lane & 15);
        int rr = r < Mm ? r : (Mm - 1);
        const float* s = gidx ? (Ab + (long)gidx[rr] * lda) : (Ab + (long)rr * lda);
        arow[rt] = s + koff;
    }
    const short* whi[4]; const short* wlo[4];
    #pragma unroll
    for (int nt = 0; nt < 4; ++nt) {
        long off = (long)(n0 + nt * 16 + (lane & 15)) * wld + koff;
        whi[nt] = Whi + off; wlo[nt] = Wlo + off;
    }

    f32x4 acc[4][4];
    #pragma unroll
    for (int rt = 0; rt < 4; ++rt)
        #pragma unroll
        for (int nt = 0; nt < 4; ++nt) acc[rt][nt] = (f32x4){0.f, 0.f, 0.f, 0.f};

    for (int kt = w * 6; kt < w * 6 + 6; ++kt) {
        const int kb = kt * 32;
        short8 ah[4], al[4];
        #pragma unroll
        for (int rt = 0; rt < 4; ++rt) {
            float4 p0 = *(const float4*)(arow[rt] + kb);
            float4 p1 = *(const float4*)(arow[rt] + kb + 4);
            cvt8(p0, p1, ah[rt], al[rt]);
        }
        #pragma unroll
        for (int nt = 0; nt < 4; ++nt) {
            short8 Bh = *(const short8*)(whi[nt] + kb);
            short8 Bl = *(const short8*)(wlo[nt] + kb);
            #pragma unroll
            for (int rt = 0; rt < 4; ++rt) {
                acc[rt][nt] = MFMA16(ah[rt], Bh, acc[rt][nt]);
                acc[rt][nt] = MFMA16(ah[rt], Bl, acc[rt][nt]);
                acc[rt][nt] = MFMA16(al[rt], Bh, acc[rt][nt]);
            }
        }
    }

    __shared__ f32x4 Lr[112][64];       // 7 writer-waves x 16 frags
    if (w > 0) {
        #pragma unroll
        for (int rt = 0; rt < 4; ++rt)
            #pragma unroll
            for (int nt = 0; nt < 4; ++nt)
                Lr[(w - 1) * 16 + rt * 4 + nt][lane] = acc[rt][nt];
    }
    __syncthreads();
    if (w == 0) {
        #pragma unroll
        for (int rt = 0; rt < 4; ++rt)
            #pragma unroll
            for (int nt = 0; nt < 4; ++nt) {
                int f = rt * 4 + nt;
                f32x4 s = acc[rt][nt];
                #pragma unroll
                for (int q = 0; q < 7; ++q) s = s + Lr[q * 16 + f][lane];
                int col = n0 + nt * 16 + (lane & 15);
                int rb  = r0 + rt * 16 + ((lane >> 4) << 2);
                #pragma unroll
                for (int r = 0; r < 4; ++r)
                    if (rb + r < Mm) C[(long)(rb + r) * ldc + col] = s[r];
            }
    }
}

// Gates (layer-0): gi/gh may live in different buffers (gi_pre hoisting).
__global__ void k_gates2(const float* __restrict__ GI, long ldgi,
                         const float* __restrict__ GH, long ldgh,
                         const float* __restrict__ h, long ldh,
                         const float* __restrict__ bih, const float* __restrict__ bhh,
                         float* __restrict__ hnew,
                         short* __restrict__ hnhi, short* __restrict__ hnlo)
{
    int t = blockIdx.x * 256 + threadIdx.x;       // 64*768
    int b = t / 768, c = t - b * 768;
    const float* gi = GI + (long)b * ldgi;
    const float* gh = GH + (long)b * ldgh;
    float ir  = gi[c]        + bih[c];
    float iz  = gi[768 + c]  + bih[768 + c];
    float in_ = gi[1536 + c] + bih[1536 + c];
    float hr  = gh[c]        + bhh[c];
    float hz  = gh[768 + c]  + bhh[768 + c];
    float hn  = gh[1536 + c] + bhh[1536 + c];
    float r  = 1.f / (1.f + expf(-(ir + hr)));
    float z_ = 1.f / (1.f + expf(-(iz + hz)));
    float n  = tanhf(in_ + r * hn);
    float hp = h[(long)b * ldh + c];
    float v = (1.f - z_) * n + z_ * hp;
    hnew[t] = v;
    short sh, sl; split1(v, sh, sl);
    hnhi[t] = sh; hnlo[t] = sl;
}

// Add bias then LayerNorm each 768-wide row of X in place (+ shadow).
__global__ void k_ln2(float* __restrict__ X, const float* __restrict__ bias,
                      const float* __restrict__ g, const float* __restrict__ be,
                      short* __restrict__ Xhi, short* __restrict__ Xlo)
{
    int row = blockIdx.x, tid = threadIdx.x;
    __shared__ float red[256];
    float* xr = X + (long)row * 768;
    float v[3];
    #pragma unroll
    for (int it = 0; it < 3; ++it) {
        int c2 = tid + it * 256;
        v[it] = xr[c2] + bias[c2];
    }
    float s = v[0] + v[1] + v[2];
    red[tid] = s; __syncthreads();
    for (int o = 128; o > 0; o >>= 1) { if (tid < o) red[tid] += red[tid + o]; __syncthreads(); }
    float mu = red[0] / 768.f;
    __syncthreads();
    float vv = 0.f;
    #pragma unroll
    for (int it = 0; it < 3; ++it) { float d = v[it] - mu; vv += d * d; }
    red[tid] = vv; __syncthreads();
    for (int o = 128; o > 0; o >>= 1) { if (tid < o) red[tid] += red[tid + o]; __syncthreads(); }
    float inv = 1.f / sqrtf(red[0] / 768.f + 1e-5f);
    #pragma unroll
    for (int it = 0; it < 3; ++it) {
        int c2 = tid + it * 256;
        float o2 = (v[it] - mu) * inv * g[c2] + be[c2];
        xr[c2] = o2;
        short sh, sl; split1(o2, sh, sl);
        Xhi[(long)row * 768 + c2] = sh;
        Xlo[(long)row * 768 + c2] = sl;
    }
}

// ---------------------------------------------------------------------------
// Fused op head with optional cg-gates-L1 prologue (do_gates).
// ---------------------------------------------------------------------------
__global__ __launch_bounds__(256) void k_ophead_fused(
    int do_gates,
    const float* __restrict__ GI,
    const float* __restrict__ bihg, const float* __restrict__ bhhg,
    const float* __restrict__ hp, long ldhp,
    float* __restrict__ cvf, short* __restrict__ cvhi, short* __restrict__ cvlo,
    const float* __restrict__ W1, const float* __restrict__ b1,
    const float* __restrict__ W2, const float* __restrict__ b2,
    float* __restrict__ op_out, int i)
{
    int b = blockIdx.x, tid = threadIdx.x;
    __shared__ float xs[768];
    __shared__ float hs[384];

    if (do_gates) {
        const float* gb = GI + (long)b * 4608;
        #pragma unroll
        for (int it = 0; it < 3; ++it) {
            int c2 = tid + it * 256;
            float ir  = gb[c2]        + bihg[c2];
            float iz  = gb[768 + c2]  + bihg[768 + c2];
            float in_ = gb[1536 + c2] + bihg[1536 + c2];
            float hr  = gb[2304 + c2] + bhhg[c2];
            float hz  = gb[3072 + c2] + bhhg[768 + c2];
            float hn  = gb[3840 + c2] + bhhg[1536 + c2];
            float r  = 1.f / (1.f + expf(-(ir + hr)));
            float z_ = 1.f / (1.f + expf(-(iz + hz)));
            float n  = tanhf(in_ + r * hn);
            float hpv = hp[(long)b * ldhp + c2];
            float v = (1.f - z_) * n + z_ * hpv;
            xs[c2] = v;
            cvf[(long)b * 768 + c2] = v;
            short sh, sl; split1(v, sh, sl);
            cvhi[(long)b * 768 + c2] = sh;
            cvlo[(long)b * 768 + c2] = sl;
        }
    } else {
        const float* xr = cvf + (long)b * 768;
        #pragma unroll
        for (int it = 0; it < 3; ++it) xs[tid + it * 256] = xr[tid + it * 256];
    }
    __syncthreads();

    for (int c = tid; c < 384; c += 256) {
        const float* wr = W1 + (long)c * 768;
        float acc = 0.f;
        #pragma unroll 8
        for (int k = 0; k < 768; k += 4) {
            float4 xv = *(const float4*)&xs[k];
            float4 wv = *(const float4*)(wr + k);
            acc += xv.x * wv.x + xv.y * wv.y + xv.z * wv.z + xv.w * wv.w;
        }
        hs[c] = fmaxf(acc + b1[c], 0.f);
    }
    __syncthreads();

    int c = tid >> 3, g = tid & 7;
    float acc = 0.f;
    if (c < OP_) {
        const float* wr = W2 + (long)c * HH_;
        #pragma unroll
        for (int t = 0; t < 12; ++t) {
            int k = (g + 8 * t) * 4;
            float4 xv = *(const float4*)&hs[k];
            float4 wv = *(const float4*)(wr + k);
            acc += xv.x * wv.x + xv.y * wv.y + xv.z * wv.z + xv.w * wv.w;
        }
    }
    acc += __shfl_xor(acc, 1);
    acc += __shfl_xor(acc, 2);
    acc += __shfl_xor(acc, 4);
    if (c < OP_ && g == 0)
        op_out[((long)b * E_ + i) * OP_ + c] = acc + b2[c];
}

// ---------------------------------------------------------------------------
// Fused od head with og-gates-L1 prologue.
// ---------------------------------------------------------------------------
__global__ __launch_bounds__(256) void k_odhead(
    const float* __restrict__ GI,
    const float* __restrict__ bihg, const float* __restrict__ bhhg,
    const float* __restrict__ hp, long ldhp,
    float* __restrict__ hx1f, short* __restrict__ hx1hi, short* __restrict__ hx1lo,
    const float* __restrict__ W1, const float* __restrict__ b1,
    const float* __restrict__ W2, const float* __restrict__ b2,
    float* __restrict__ od_base, long ldl,
    float* __restrict__ prev, int i,
    const float* __restrict__ pcb, const float* __restrict__ pnb,
    short* __restrict__ pvhi, short* __restrict__ pvlo,
    int do_final)
{
    int b = blockIdx.x, tid = threadIdx.x;
    __shared__ float xs[768];
    __shared__ float ps[768];
    __shared__ float hidL[24];
    __shared__ float lg[48];
    __shared__ float red[256];
    __shared__ int s_oidx;

    {
        const float* gb = GI + (long)b * 4608;
        #pragma unroll
        for (int it = 0; it < 3; ++it) {
            int c2 = tid + it * 256;
            float ir  = gb[c2]        + bihg[c2];
            float iz  = gb[768 + c2]  + bihg[768 + c2];
            float in_ = gb[1536 + c2] + bihg[1536 + c2];
            float hr  = gb[2304 + c2] + bhhg[c2];
            float hz  = gb[3072 + c2] + bhhg[768 + c2];
            float hn  = gb[3840 + c2] + bhhg[1536 + c2];
            float r  = 1.f / (1.f + expf(-(ir + hr)));
            float z_ = 1.f / (1.f + expf(-(iz + hz)));
            float n  = tanhf(in_ + r * hn);
            float hpv = hp[(long)b * ldhp + c2];
            float v = (1.f - z_) * n + z_ * hpv;
            xs[c2] = v;
            hx1f[(long)b * 768 + c2] = v;
            short sh, sl; split1(v, sh, sl);
            hx1hi[(long)b * 768 + c2] = sh;
            hx1lo[(long)b * 768 + c2] = sl;
        }
    }
    __syncthreads();

    int c = tid >> 3, g = tid & 7;
    float acc = 0.f;
    if (c < 24) {
        const float* wr = W1 + (long)c * 768;
        #pragma unroll
        for (int t = 0; t < 24; ++t) {
            int k = (g + 8 * t) * 4;
            float4 xv = *(const float4*)&xs[k];
            float4 wv = *(const float4*)(wr + k);
            acc += xv.x * wv.x + xv.y * wv.y + xv.z * wv.z + xv.w * wv.w;
        }
    }
    acc += __shfl_xor(acc, 1);
    acc += __shfl_xor(acc, 2);
    acc += __shfl_xor(acc, 4);
    if (c < 24 && g == 0) hidL[c] = fmaxf(acc + b1[c], 0.f);
    __syncthreads();

    if (tid < 48) {
        float a2 = b2[tid];
        const float* w2 = W2 + tid * 24;
        #pragma unroll
        for (int k = 0; k < 24; ++k) a2 += hidL[k] * w2[k];
        lg[tid] = a2;
        od_base[(long)b * ldl + tid] = a2;
    }

    long poff = ((long)b * E_ + i) * 768;
    float* prow = prev + poff;
    float m = -3.4e38f;
    #pragma unroll
    for (int it = 0; it < 3; ++it) m = fmaxf(m, prow[tid + it * 256]);
    red[tid] = m; __syncthreads();
    for (int o = 128; o > 0; o >>= 1) { if (tid < o) red[tid] = fmaxf(red[tid], red[tid + o]); __syncthreads(); }
    float m0 = red[0];

    if (tid == 0) {      // first-max tie semantics (matches jnp.argmax)
        float best = lg[0]; int bi = 0;
        for (int k2 = 1; k2 < K_; ++k2) { float v = lg[k2]; if (v > best) { best = v; bi = k2; } }
        s_oidx = bi;
    }
    __syncthreads();
    int oidx = s_oidx;
    bool empty0 = (m0 == 0.0f);
    bool cond = (oidx == 0) && empty0;
    if (cond) {
        #pragma unroll
        for (int it = 0; it < 3; ++it) {
            int c2 = tid + it * 256;
            float v = xs[c2];
            prow[c2] = v;
            short sh, sl; split1(v, sh, sl);
            pvhi[poff + c2] = sh; pvlo[poff + c2] = sl;
        }
    }
    __syncthreads();

    if (!do_final) return;

    float mfin;
    if (cond) {
        float mx = -3.4e38f;
        #pragma unroll
        for (int it = 0; it < 3; ++it) mx = fmaxf(mx, xs[tid + it * 256]);
        red[tid] = mx; __syncthreads();
        for (int o = 128; o > 0; o >>= 1) { if (tid < o) red[tid] = fmaxf(red[tid], red[tid + o]); __syncthreads(); }
        mfin = red[0];
    } else {
        mfin = m0;
    }

    const float* src;
    if (oidx < C_)            src = pcb + (long)oidx * 768;
    else if (oidx < C_ + M_)  src = pnb + ((long)b * M_ + (oidx - C_)) * 768;
    else                      src = prev + ((long)b * E_ + (oidx - C_ - M_)) * 768;
    #pragma unroll
    for (int it = 0; it < 3; ++it) ps[tid + it * 256] = src[tid + it * 256];
    __syncthreads();

    if (mfin == 0.0f) {
        #pragma unroll
        for (int it = 0; it < 3; ++it) {
            int c2 = tid + it * 256;
            float v = ps[c2];
            prow[c2] = v;
            short sh, sl; split1(v, sh, sl);
            pvhi[poff + c2] = sh; pvlo[poff + c2] = sl;
        }
    }
}

// Build num_vec: for (b,m) find first/last position with number_mask==m+1
__global__ void k_numvec(const float* __restrict__ inp, const int* __restrict__ nmask,
                         float* __restrict__ numvec)
{
    int b = blockIdx.x / M_, m = blockIdx.x % M_;
    int tid = threadIdx.x;
    int fmin = S_, lmax = -1;
    for (int s = tid; s < S_; s += 256) {
        if (nmask[b * S_ + s] == m + 1) {
            if (s < fmin) fmin = s;
            if (s > lmax) lmax = s;
        }
    }
    __shared__ int sf[256], sl[256];
    sf[tid] = fmin; sl[tid] = lmax; __syncthreads();
    for (int o = 128; o > 0; o >>= 1) {
        if (tid < o) {
            sf[tid] = min(sf[tid], sf[tid + o]);
            sl[tid] = max(sl[tid], sl[tid + o]);
        }
        __syncthreads();
    }
    int first = sf[0], last = sl[0];
    bool exists = (last >= 0);
    if (!exists) { first = 0; last = 0; }
    const float* fv = inp + ((long)b * S_ + first) * H_;
    const float* lv = inp + ((long)b * S_ + last) * H_;
    float* dst = numvec + ((long)b * M_ + m) * H2_;
    for (int h = tid; h < H_; h += 256) {
        dst[h]      = exists ? fv[h] : 0.f;
        dst[H_ + h] = exists ? lv[h] : 0.f;
    }
}

__global__ void k_copy_cv(const float* __restrict__ inp, float* __restrict__ cvv,
                          short* __restrict__ cvhi, short* __restrict__ cvlo)
{
    int b = blockIdx.x;
    for (int h = threadIdx.x; h < H_; h += 256) {
        float v = inp[(long)b * S_ * H_ + h];
        cvv[b * H_ + h] = v;
        short sh, sl; split1(v, sh, sl);
        cvhi[b * H_ + h] = sh; cvlo[b * H_ + h] = sl;
    }
}

// ---------------------------------------------------------------------------
extern "C" void kernel_launch(void* const* d_in, const int* in_sizes, int n_in,
                              void* d_out, int out_size, void* d_ws, size_t ws_size,
                              hipStream_t stream)
{
    const float* inp    = (const float*)d_in[0];
    const int*   nmask  = (const int*)  d_in[3];
    const int*   gops   = (const int*)  d_in[4];
    const int*   gopd   = (const int*)  d_in[5];
    const float* constv = (const float*)d_in[6];
    const float* opv    = (const float*)d_in[7];
    const float* opj_W  = (const float*)d_in[8];
    const float* opj_b  = (const float*)d_in[9];
    const float* opj_g  = (const float*)d_in[10];
    const float* opj_be = (const float*)d_in[11];
    const float* odj_W  = (const float*)d_in[12];
    const float* odj_b  = (const float*)d_in[13];
    const float* odj_g  = (const float*)d_in[14];
    const float* odj_be = (const float*)d_in[15];
    const float* opc_W1 = (const float*)d_in[16];
    const float* opc_b1 = (const float*)d_in[17];
    const float* opc_W2 = (const float*)d_in[18];
    const float* opc_b2 = (const float*)d_in[19];
    const float* odc_W1 = (const float*)d_in[20];
    const float* odc_b1 = (const float*)d_in[21];
    const float* odc_W2 = (const float*)d_in[22];
    const float* odc_b2 = (const float*)d_in[23];
    const float* og_Wih = (const float*)d_in[24];
    const float* og_Whh = (const float*)d_in[25];
    const float* og_bih = (const float*)d_in[26];
    const float* og_bhh = (const float*)d_in[27];
    const float* cg_Wih = (const float*)d_in[28];
    const float* cg_Whh = (const float*)d_in[29];
    const float* cg_bih = (const float*)d_in[30];
    const float* cg_bhh = (const float*)d_in[31];

    float* op_out = (float*)d_out;                  // (B, E, OP)
    float* od_out = op_out + (long)B_ * E_ * OP_;   // (B, E, A, K)

    // ---- workspace partition ----
    float* ws      = (float*)d_ws;
    float* num_vec = ws; ws += (long)B_ * M_ * H2_;       // 1024x1536
    float* pn      = ws; ws += (long)B_ * M_ * H_;        // 1024x768
    float* pcb     = ws; ws += (long)64 * H_;             // 24 used (pad 64)
    float* gopv    = ws; ws += (long)B_ * E_ * H_;        // 512x768
    float* prev    = ws; ws += (long)B_ * E_ * H_;
    float* gigh    = ws; ws += (long)B_ * 4608;           // gi | gh
    float* gi_pre  = ws; ws += (long)B_ * E_ * G3_;       // 512x2304
    float* cv      = ws; ws += (long)B_ * H_;
    float* h0      = ws; ws += (long)B_ * H_;
    float* hx0     = ws; ws += (long)B_ * H_;
    float* hx1     = ws; ws += (long)B_ * H_;

    // bf16 hi/lo shadows (shorts; all sizes even)
    auto alloc_s = [&](long elems) -> short* {
        short* p = (short*)ws; ws += elems / 2; return p;
    };
    const long nOG = (long)2 * G3_ * H_;   // per GRU stack (2 layers)
    short* og_ih_hi = alloc_s(nOG); short* og_ih_lo = alloc_s(nOG);
    short* og_hh_hi = alloc_s(nOG); short* og_hh_lo = alloc_s(nOG);
    short* cg_ih_hi = alloc_s(nOG); short* cg_ih_lo = alloc_s(nOG);
    short* cg_hh_hi = alloc_s(nOG); short* cg_hh_lo = alloc_s(nOG);
    const long nPJ = (long)H_ * H2_;
    short* odj_hi = alloc_s(nPJ); short* odj_lo = alloc_s(nPJ);
    short* opj_hi = alloc_s(nPJ); short* opj_lo = alloc_s(nPJ);
    short* pn_hi  = alloc_s((long)B_ * M_ * H_); short* pn_lo  = alloc_s((long)B_ * M_ * H_);
    short* pc_hi  = alloc_s((long)64 * H_);      short* pc_lo  = alloc_s((long)64 * H_);
    short* gv_hi  = alloc_s((long)B_ * E_ * H_); short* gv_lo  = alloc_s((long)B_ * E_ * H_);
    short* pv_hi  = alloc_s((long)B_ * E_ * H_); short* pv_lo  = alloc_s((long)B_ * E_ * H_);
    short* cv_hi  = alloc_s((long)B_ * H_);      short* cv_lo  = alloc_s((long)B_ * H_);
    short* h0_hi  = alloc_s((long)B_ * H_);      short* h0_lo  = alloc_s((long)B_ * H_);
    short* hx0_hi = alloc_s((long)B_ * H_);      short* hx0_lo = alloc_s((long)B_ * H_);
    short* hx1_hi = alloc_s((long)B_ * H_);      short* hx1_lo = alloc_s((long)B_ * H_);

    hipMemsetAsync(prev, 0, (size_t)B_ * E_ * H_ * sizeof(float), stream);
    hipMemsetAsync(pv_hi, 0, (size_t)2 * B_ * E_ * H_ * sizeof(short), stream);

    // ---- weight pre-split (single dispatch over 6 regions) ----
    {
        int nOG4 = (int)(nOG / 4), nPJ4 = (int)(nPJ / 4);
        int e0 = nOG4, e1 = 2 * nOG4, e2 = 3 * nOG4, e3 = 4 * nOG4;
        int e4 = e3 + nPJ4, e5 = e4 + nPJ4;
        k_split_all<<<(e5 + 255) / 256, 256, 0, stream>>>(
            og_Wih, og_ih_hi, og_ih_lo, e0,
            og_Whh, og_hh_hi, og_hh_lo, e1,
            cg_Wih, cg_ih_hi, cg_ih_lo, e2,
            cg_Whh, cg_hh_hi, cg_hh_lo, e3,
            odj_W,  odj_hi,  odj_lo,  e4,
            opj_W,  opj_hi,  opj_lo,  e5);
    }

    // ---- preprocessing ----
    k_numvec<<<B_ * M_, 256, 0, stream>>>(inp, nmask, num_vec);

    k_proj_mfma<<<dim3(12, 16), 512, 0, stream>>>(num_vec, H2_, nullptr, 1024,
                                                  odj_hi, odj_lo, H2_, pn, H_);
    k_ln2<<<1024, 256, 0, stream>>>(pn, odj_b, odj_g, odj_be, pn_hi, pn_lo);

    k_proj_mfma<<<dim3(12, 1), 512, 0, stream>>>(constv, H2_, nullptr, C_,
                                                 odj_hi, odj_lo, H2_, pcb, H_);
    k_ln2<<<C_, 256, 0, stream>>>(pcb, odj_b, odj_g, odj_be, pc_hi, pc_lo);

    k_proj_mfma<<<dim3(12, 8), 512, 0, stream>>>(opv, H2_, gops, 512,
                                                 opj_hi, opj_lo, H2_, gopv, H_);
    k_ln2<<<512, 256, 0, stream>>>(gopv, opj_b, opj_g, opj_be, gv_hi, gv_lo);

    // Precompute gi for all (b,i) j==0 og-layer0 calls (off critical chain)
    k_gi_pre<<<dim3(72, 8), 512, 0, stream>>>(gv_hi, gv_lo, og_ih_hi, og_ih_lo, gi_pre);

    k_copy_cv<<<B_, 256, 0, stream>>>(inp, cv, cv_hi, cv_lo);

    // ---- decode loop ----
    const long ldE = (long)E_ * H_;
    const long lW  = (long)G3_ * H_;   // layer-1 weight offset

    for (int i = 0; i < E_; ++i) {
        if (i > 0) {
            const float* hrow = prev + (long)(i - 1) * H_;
            const short* hrhi = pv_hi + (long)(i - 1) * H_;
            const short* hrlo = pv_lo + (long)(i - 1) * H_;
            k_gru_mfma<<<144, 512, 0, stream>>>(0, cv_hi, cv_lo, H_, 0, nullptr, 0, 0,
                                                nullptr, nullptr, nullptr, nullptr, nullptr, nullptr,
                                                hrhi, hrlo, ldE,
                                                cg_ih_hi, cg_ih_lo, cg_hh_hi, cg_hh_lo, gigh);
            k_gates2<<<192, 256, 0, stream>>>(gigh, 4608, gigh + 2304, 4608,
                                              hrow, ldE, cg_bih, cg_bhh, h0, h0_hi, h0_lo);
            k_gru_mfma<<<144, 512, 0, stream>>>(0, h0_hi, h0_lo, H_, 0, nullptr, 0, 0,
                                                nullptr, nullptr, nullptr, nullptr, nullptr, nullptr,
                                                hrhi, hrlo, ldE,
                                                cg_ih_hi + lW, cg_ih_lo + lW,
                                                cg_hh_hi + lW, cg_hh_lo + lW, gigh);
            k_ophead_fused<<<B_, 256, 0, stream>>>(1, gigh, cg_bih + G3_, cg_bhh + G3_,
                                                   hrow, ldE, cv, cv_hi, cv_lo,
                                                   opc_W1, opc_b1, opc_W2, opc_b2, op_out, i);
        } else {
            k_ophead_fused<<<B_, 256, 0, stream>>>(0, gigh, cg_bih, cg_bhh,
                                                   cv, H_, cv, cv_hi, cv_lo,
                                                   opc_W1, opc_b1, opc_W2, opc_b2, op_out, i);
        }

        for (int j = 0; j < A_; ++j) {
            const float* hp0 = (j == 0) ? cv : hx0;
            const float* hp1 = (j == 0) ? cv : hx1;
            const short* hp0hi = (j == 0) ? cv_hi : hx0_hi;
            const short* hp0lo = (j == 0) ? cv_lo : hx0_lo;
            const short* hp1hi = (j == 0) ? cv_hi : hx1_hi;
            const short* hp1lo = (j == 0) ? cv_lo : hx1_lo;

            if (j == 0) {
                // gi half precomputed in gi_pre; only gh here (72 blocks)
                k_gru_mfma<<<72, 512, 0, stream>>>(1, nullptr, nullptr, 0, 0, nullptr, 0, 0,
                                                   nullptr, nullptr, nullptr, nullptr, nullptr, nullptr,
                                                   hp0hi, hp0lo, H_,
                                                   og_ih_hi, og_ih_lo, og_hh_hi, og_hh_lo, gigh);
                k_gates2<<<192, 256, 0, stream>>>(gi_pre + (long)i * G3_, (long)E_ * G3_,
                                                  gigh + 2304, 4608,
                                                  hp0, H_, og_bih, og_bhh, hx0, hx0_hi, hx0_lo);
            } else {
                k_gru_mfma<<<144, 512, 0, stream>>>(0, nullptr, nullptr, 0, 1, gopd, i, j - 1,
                                                    pc_hi, pc_lo, pn_hi, pn_lo, pv_hi, pv_lo,
                                                    hp0hi, hp0lo, H_,
                                                    og_ih_hi, og_ih_lo, og_hh_hi, og_hh_lo, gigh);
                k_gates2<<<192, 256, 0, stream>>>(gigh, 4608, gigh + 2304, 4608,
                                                  hp0, H_, og_bih, og_bhh, hx0, hx0_hi, hx0_lo);
            }
            k_gru_mfma<<<144, 512, 0, stream>>>(0, hx0_hi, hx0_lo, H_, 0, nullptr, 0, 0,
                                                nullptr, nullptr, nullptr, nullptr, nullptr, nullptr,
                                                hp1hi, hp1lo, H_,
                                                og_ih_hi + lW, og_ih_lo + lW,
                                                og_hh_hi + lW, og_hh_lo + lW, gigh);

            float* od_base = od_out + ((long)i * A_ + j) * K_;
            k_odhead<<<B_, 256, 0, stream>>>(gigh, og_bih + G3_, og_bhh + G3_,
                                             hp1, H_, hx1, hx1_hi, hx1_lo,
                                             odc_W1, odc_b1, odc_W2, odc_b2,
                                             od_base, (long)E_ * A_ * K_,
                                             prev, i, pcb, pn, pv_hi, pv_lo,
                                             (j == A_ - 1) ? 1 : 0);
        }
    }
}